// Round 2
// baseline (30513.699 us; speedup 1.0000x reference)
//
#include <hip/hip_runtime.h>
#include <hip/hip_cooperative_groups.h>
#include <cstdint>

namespace cg = cooperative_groups;

#define S_  128
#define Tt_ 64
#define V_  32000

typedef _Float16 h8 __attribute__((ext_vector_type(8)));
typedef float    f4 __attribute__((ext_vector_type(4)));

#define MFMA16(a,b,c) __builtin_amdgcn_mfma_f32_16x16x32_f16((a),(b),(c),0,0,0)

struct KP {
  const int* itoks; const int* target; const int* tfm;
  const float* in_emb; const float* out_emb;
  const float* encWih; const float* encWhh; const float* encbih; const float* encbhh;
  const float* decWih; const float* decWhh; const float* decbih; const float* decbhh;
  const float* Wout; const float* bout;
  float* out;
  _Float16 *seqH, *seqL;    // 129 slots x 32 x 1024
  _Float16 *he1H, *he1L;    // 2 slots  x 32 x 1024 (encoder layer1 h parity)
  _Float16 *hd0H, *hd0L;    // 2 slots (decoder layer0 h parity)
  _Float16 *hd1H, *hd1L;    // 2 slots (decoder layer1 h parity)
  unsigned long long* amax; // 32
};

__device__ __forceinline__ void split8p(const float* __restrict__ p, h8& hi, h8& lo) {
  f4 a = *(const f4*)p;
  f4 b = *(const f4*)(p + 4);
#pragma unroll
  for (int i = 0; i < 4; i++) {
    _Float16 h0 = (_Float16)a[i];
    hi[i] = h0; lo[i] = (_Float16)((a[i] - (float)h0) * 2048.0f);
    _Float16 h1 = (_Float16)b[i];
    hi[i+4] = h1; lo[i+4] = (_Float16)((b[i] - (float)h1) * 2048.0f);
  }
}

// LDS weight addressing: 16 rows x 2048 halves, XOR-swizzle 16B granules (T2-style)
__device__ __forceinline__ int wadr(int row, int k) {
  return row * 2048 + ((((k << 1) ^ ((row & 7) << 4))) >> 1);
}

// Preload this block's 16 gate-rows of [Wih ; Whh] (fp32 -> split fp16 pair) into LDS.
__device__ void preload_enc(const float* __restrict__ Wih, const float* __restrict__ Whh,
                            int blk, int tid, _Float16* sWH, _Float16* sWL) {
#pragma unroll 4
  for (int it = 0; it < 32; ++it) {
    int lin = (it * 256 + tid) * 4;      // element in [0, 16*2048)
    int j16 = lin >> 11;
    int k   = lin & 2047;
    int g = j16 >> 2, u = j16 & 3;
    int grow = g * 1024 + blk * 4 + u;
    const float* src = (k < 1024) ? (Wih + (size_t)grow * 1024 + k)
                                  : (Whh + (size_t)grow * 1024 + (k - 1024));
    f4 x = *(const f4*)src;
#pragma unroll
    for (int q = 0; q < 4; q++) {
      _Float16 hh = (_Float16)x[q];
      sWH[wadr(j16, k + q)] = hh;
      sWL[wadr(j16, k + q)] = (_Float16)((x[q] - (float)hh) * 2048.0f);
    }
  }
}

// Gate GEMM phase: gates[32 x 16rows] = [x ; h] @ Brows^T, K=2048 concat.
// XMODE: 0 = x from split buffer (xH,xL); 1 = gather in_emb[itoks[b,step]]; 2 = decoder token rule on out_emb.
// BMODE: 0 = B from LDS (encoder); 1 = B streamed fp32 + inline split (decoder).
template <int XMODE, int BMODE>
__device__ void gates_phase(const _Float16* sWH, const _Float16* sWL, float* sScr,
                            const float* __restrict__ WihF, const float* __restrict__ WhhF,
                            const _Float16* __restrict__ xH, const _Float16* __restrict__ xL,
                            const float* __restrict__ emb, const int* __restrict__ tokarr,
                            const int* __restrict__ tfm, const unsigned long long* __restrict__ amax,
                            int step,
                            const _Float16* __restrict__ hHb, const _Float16* __restrict__ hLb,
                            int blk, int tid) {
  int w = tid >> 6, lane = tid & 63;
  int kbase = w * 512;
  bool xp = (w < 2);                 // waves 0,1: x-part (k<1024); waves 2,3: h-part
  int j16 = lane & 15;
  int g_ = j16 >> 2, u_ = j16 & 3;
  int grow = g_ * 1024 + blk * 4 + u_;

  int tok0 = 0, tok1 = 0;
  if (XMODE == 1) {
    tok0 = tokarr[(lane & 15) * S_ + step];
    tok1 = tokarr[(16 + (lane & 15)) * S_ + step];
  } else if (XMODE == 2) {
    int b0 = lane & 15, b1 = 16 + (lane & 15);
    if (step == 0)            { tok0 = tokarr[b0 * Tt_];        tok1 = tokarr[b1 * Tt_]; }
    else if (tfm[step] > 0)   { tok0 = tokarr[b0 * Tt_ + step]; tok1 = tokarr[b1 * Tt_ + step]; }
    else                      { tok0 = (int)(~(unsigned)amax[b0]); tok1 = (int)(~(unsigned)amax[b1]); }
  }

  f4 accH[2] = {}, accM[2] = {};
  for (int ks = 0; ks < 16; ++ks) {
    int kk = kbase + ks * 32 + (lane >> 4) * 8;   // global k in [0,2048)
    h8 Bh, Bl;
    if (BMODE == 0) {
      Bh = *(const h8*)(sWH + wadr(j16, kk));
      Bl = *(const h8*)(sWL + wadr(j16, kk));
    } else {
      const float* src = xp ? (WihF + (size_t)grow * 1024 + kk)
                            : (WhhF + (size_t)grow * 1024 + (kk - 1024));
      split8p(src, Bh, Bl);
    }
#pragma unroll
    for (int mt = 0; mt < 2; ++mt) {
      int brow = mt * 16 + (lane & 15);
      h8 Ah, Al;
      if (xp) {
        if (XMODE == 0) {
          Ah = *(const h8*)(xH + (size_t)brow * 1024 + kk);
          Al = *(const h8*)(xL + (size_t)brow * 1024 + kk);
        } else {
          int tk = mt ? tok1 : tok0;
          split8p(emb + (size_t)tk * 1024 + kk, Ah, Al);
        }
      } else {
        Ah = *(const h8*)(hHb + (size_t)brow * 1024 + (kk - 1024));
        Al = *(const h8*)(hLb + (size_t)brow * 1024 + (kk - 1024));
      }
      accH[mt] = MFMA16(Ah, Bh, accH[mt]);
      accM[mt] = MFMA16(Ah, Bl, accM[mt]);
      accM[mt] = MFMA16(Al, Bh, accM[mt]);
    }
  }
  // partials -> LDS scratch [w][b][j16]
#pragma unroll
  for (int mt = 0; mt < 2; ++mt)
#pragma unroll
    for (int r = 0; r < 4; ++r) {
      int b = mt * 16 + (lane >> 4) * 4 + r;
      sScr[w * 512 + b * 16 + j16] = accH[mt][r] + accM[mt][r] * (1.0f / 2048.0f);
    }
}

// Reduce partials, apply LSTM cell, write split h (and optional second copy).
__device__ void cell_finish(float* sScr, int blk, int tid,
                            const float* __restrict__ bih, const float* __restrict__ bhh,
                            float& c,
                            _Float16* __restrict__ oH, _Float16* __restrict__ oL,
                            _Float16* __restrict__ oH2, _Float16* __restrict__ oL2) {
  __syncthreads();
  if (tid < 128) {
    int u = tid >> 5, b = tid & 31;
    float g[4];
#pragma unroll
    for (int gg = 0; gg < 4; ++gg) {
      int j = gg * 4 + u;
      float s = sScr[0 * 512 + b * 16 + j] + sScr[1 * 512 + b * 16 + j]
              + sScr[2 * 512 + b * 16 + j] + sScr[3 * 512 + b * 16 + j];
      int grow = gg * 1024 + blk * 4 + u;
      g[gg] = s + bih[grow] + bhh[grow];
    }
    float ii = 1.0f / (1.0f + expf(-g[0]));
    float ff = 1.0f / (1.0f + expf(-g[1]));
    float gt = tanhf(g[2]);
    float oo = 1.0f / (1.0f + expf(-g[3]));
    c = ff * c + ii * gt;
    float hn = oo * tanhf(c);
    _Float16 hh = (_Float16)hn;
    _Float16 hl = (_Float16)((hn - (float)hh) * 2048.0f);
    int col = blk * 4 + u;
    oH[(size_t)b * 1024 + col] = hh;
    oL[(size_t)b * 1024 + col] = hl;
    if (oH2) { oH2[(size_t)b * 1024 + col] = hh; oL2[(size_t)b * 1024 + col] = hl; }
  }
  __syncthreads();
}

// Vocab projection: logits = h @ Wout^T + b; write out row step+1; packed atomic argmax.
__device__ void proj_phase(const _Float16* __restrict__ hH, const _Float16* __restrict__ hL,
                           const float* __restrict__ Wout, const float* __restrict__ bout,
                           float* __restrict__ out, unsigned long long* __restrict__ amax,
                           int step, int blk, int tid) {
  int w = tid >> 6, lane = tid & 63;
  int gw = blk * 4 + w;
  if (gw < 1000) {
    int v0 = gw * 32;
    f4 accH[2][2] = {}, accM[2][2] = {};
    for (int ks = 0; ks < 32; ++ks) {
      int kk = ks * 32 + (lane >> 4) * 8;
      h8 Ah[2], Al[2];
#pragma unroll
      for (int mt = 0; mt < 2; ++mt) {
        int brow = mt * 16 + (lane & 15);
        Ah[mt] = *(const h8*)(hH + (size_t)brow * 1024 + kk);
        Al[mt] = *(const h8*)(hL + (size_t)brow * 1024 + kk);
      }
#pragma unroll
      for (int jt = 0; jt < 2; ++jt) {
        int vrow = v0 + jt * 16 + (lane & 15);
        h8 Bh, Bl;
        split8p(Wout + (size_t)vrow * 1024 + kk, Bh, Bl);
#pragma unroll
        for (int mt = 0; mt < 2; ++mt) {
          accH[mt][jt] = MFMA16(Ah[mt], Bh, accH[mt][jt]);
          accM[mt][jt] = MFMA16(Ah[mt], Bl, accM[mt][jt]);
          accM[mt][jt] = MFMA16(Al[mt], Bh, accM[mt][jt]);
        }
      }
    }
#pragma unroll
    for (int mt = 0; mt < 2; ++mt)
#pragma unroll
      for (int jt = 0; jt < 2; ++jt) {
        int vcol = v0 + jt * 16 + (lane & 15);
        float bias = bout[vcol];
        float vr[4];
#pragma unroll
        for (int r = 0; r < 4; ++r) {
          int b = mt * 16 + (lane >> 4) * 4 + r;
          float v = accH[mt][jt][r] + accM[mt][jt][r] * (1.0f / 2048.0f) + bias;
          out[(size_t)b * (Tt_ * V_) + (size_t)(step + 1) * V_ + vcol] = v;
          vr[r] = v;
        }
#pragma unroll
        for (int r = 0; r < 4; ++r) {
          float v = vr[r];
          unsigned id = (unsigned)vcol;
#pragma unroll
          for (int off = 1; off < 16; off <<= 1) {
            float ov = __shfl_xor(v, off, 64);
            unsigned oi = __shfl_xor(id, off, 64);
            if (ov > v || (ov == v && oi < id)) { v = ov; id = oi; }
          }
          if ((lane & 15) == 0) {
            unsigned kb = __float_as_uint(v);
            kb = (kb & 0x80000000u) ? ~kb : (kb | 0x80000000u);
            unsigned long long key = ((unsigned long long)kb << 32) | (unsigned)(~id);
            int b = mt * 16 + (lane >> 4) * 4 + r;
            atomicMax(&amax[b], key);
          }
        }
      }
  }
}

__global__ void __launch_bounds__(256, 1) voice_coop(KP P) {
  cg::grid_group grid = cg::this_grid();
  __shared__ _Float16 sWH[16 * 2048];   // 64 KB
  __shared__ _Float16 sWL[16 * 2048];   // 64 KB
  __shared__ float    sScr[4 * 512];    // 8 KB
  int blk = blockIdx.x, tid = threadIdx.x;
  float cA = 0.0f, cB = 0.0f;           // layer0 / layer1 cell state (threads 0-127)

  // ---- init: zero out[:,0,:], seq slot 0, he1 slot 0 ----
  for (unsigned idx = blk * 256 + tid; idx < 32u * V_; idx += 65536u) {
    unsigned b = idx / V_, v = idx - b * V_;
    P.out[(size_t)b * (Tt_ * V_) + v] = 0.0f;
  }
  for (int idx = blk * 256 + tid; idx < 32 * 1024; idx += 65536) {
    P.seqH[idx] = (_Float16)0.0f; P.seqL[idx] = (_Float16)0.0f;
    P.he1H[idx] = (_Float16)0.0f; P.he1L[idx] = (_Float16)0.0f;
  }
  grid.sync();

  // ---- encoder: 2 layers, LDS-resident weights, 128 recurrent steps each ----
  for (int l = 0; l < 2; ++l) {
    const float* Wih = P.encWih + (size_t)l * 4096 * 1024;
    const float* Whh = P.encWhh + (size_t)l * 4096 * 1024;
    const float* bih = P.encbih + (size_t)l * 4096;
    const float* bhh = P.encbhh + (size_t)l * 4096;
    preload_enc(Wih, Whh, blk, tid, sWH, sWL);
    grid.sync();
    for (int t = 0; t < 128; ++t) {
      if (l == 0) {
        // A1 = in_emb[itoks[b,t]] (gather), A2 = seq[t] (h_{t-1}); out -> seq[t+1]
        gates_phase<1, 0>(sWH, sWL, sScr, nullptr, nullptr, nullptr, nullptr,
                          P.in_emb, P.itoks, nullptr, nullptr, t,
                          P.seqH + (size_t)t * 32768, P.seqL + (size_t)t * 32768, blk, tid);
        bool last = (t == 127);
        cell_finish(sScr, blk, tid, bih, bhh, cA,
                    P.seqH + (size_t)(t + 1) * 32768, P.seqL + (size_t)(t + 1) * 32768,
                    last ? P.hd0H : nullptr, last ? P.hd0L : nullptr);
      } else {
        // A1 = seq[t+1] (= y0[t]), A2 = he1[t&1]; out -> he1[(t&1)^1]
        int pp = t & 1;
        gates_phase<0, 0>(sWH, sWL, sScr, nullptr, nullptr,
                          P.seqH + (size_t)(t + 1) * 32768, P.seqL + (size_t)(t + 1) * 32768,
                          nullptr, nullptr, nullptr, nullptr, t,
                          P.he1H + (size_t)pp * 32768, P.he1L + (size_t)pp * 32768, blk, tid);
        bool last = (t == 127);
        cell_finish(sScr, blk, tid, bih, bhh, cB,
                    P.he1H + (size_t)(pp ^ 1) * 32768, P.he1L + (size_t)(pp ^ 1) * 32768,
                    last ? P.hd1H : nullptr, last ? P.hd1L : nullptr);
      }
      grid.sync();
    }
  }

  // ---- decoder: 63 steps x {cell0, cell1, proj} ----
  const float* dWih0 = P.decWih;
  const float* dWhh0 = P.decWhh;
  const float* dWih1 = P.decWih + (size_t)4096 * 1024;
  const float* dWhh1 = P.decWhh + (size_t)4096 * 1024;
  for (int i = 0; i < 63; ++i) {
    int p = i & 1;
    // cell0: A1 = out_emb[token rule], A2 = hd0[p] -> hd0[p^1]; c = cA (carried from encoder l0 final)
    gates_phase<2, 1>(nullptr, nullptr, sScr, dWih0, dWhh0, nullptr, nullptr,
                      P.out_emb, P.target, P.tfm, P.amax, i,
                      P.hd0H + (size_t)p * 32768, P.hd0L + (size_t)p * 32768, blk, tid);
    cell_finish(sScr, blk, tid, P.decbih, P.decbhh, cA,
                P.hd0H + (size_t)(p ^ 1) * 32768, P.hd0L + (size_t)(p ^ 1) * 32768,
                nullptr, nullptr);
    grid.sync();
    // cell1: A1 = hd0[p^1], A2 = hd1[p] -> hd1[p^1]; c = cB; also reset amax for this step's proj
    if (blk == 0 && tid < 32) P.amax[tid] = 0ull;
    gates_phase<0, 1>(nullptr, nullptr, sScr, dWih1, dWhh1,
                      P.hd0H + (size_t)(p ^ 1) * 32768, P.hd0L + (size_t)(p ^ 1) * 32768,
                      nullptr, nullptr, nullptr, nullptr, i,
                      P.hd1H + (size_t)p * 32768, P.hd1L + (size_t)p * 32768, blk, tid);
    cell_finish(sScr, blk, tid, P.decbih + 4096, P.decbhh + 4096, cB,
                P.hd1H + (size_t)(p ^ 1) * 32768, P.hd1L + (size_t)(p ^ 1) * 32768,
                nullptr, nullptr);
    grid.sync();
    proj_phase(P.hd1H + (size_t)(p ^ 1) * 32768, P.hd1L + (size_t)(p ^ 1) * 32768,
               P.Wout, P.bout, P.out, P.amax, i, blk, tid);
    grid.sync();
  }
}

// ---------------- host ----------------

extern "C" void kernel_launch(void* const* d_in, const int* in_sizes, int n_in,
                              void* d_out, int out_size, void* d_ws, size_t ws_size,
                              hipStream_t stream) {
  KP P;
  P.itoks   = (const int*)d_in[0];
  P.target  = (const int*)d_in[1];
  P.tfm     = (const int*)d_in[2];
  P.in_emb  = (const float*)d_in[3];
  P.out_emb = (const float*)d_in[4];
  P.encWih  = (const float*)d_in[5];
  P.encWhh  = (const float*)d_in[6];
  P.encbih  = (const float*)d_in[7];
  P.encbhh  = (const float*)d_in[8];
  P.decWih  = (const float*)d_in[9];
  P.decWhh  = (const float*)d_in[10];
  P.decbih  = (const float*)d_in[11];
  P.decbhh  = (const float*)d_in[12];
  P.Wout    = (const float*)d_in[13];
  P.bout    = (const float*)d_in[14];
  P.out     = (float*)d_out;

  char* ws = (char*)d_ws;
  size_t off = 0;
  auto alloc = [&](size_t bytes) { void* p = ws + off; off += (bytes + 255) & ~(size_t)255; return p; };
  P.seqH = (_Float16*)alloc((size_t)129 * 32768 * 2);
  P.seqL = (_Float16*)alloc((size_t)129 * 32768 * 2);
  P.he1H = (_Float16*)alloc((size_t)2 * 32768 * 2);
  P.he1L = (_Float16*)alloc((size_t)2 * 32768 * 2);
  P.hd0H = (_Float16*)alloc((size_t)2 * 32768 * 2);
  P.hd0L = (_Float16*)alloc((size_t)2 * 32768 * 2);
  P.hd1H = (_Float16*)alloc((size_t)2 * 32768 * 2);
  P.hd1L = (_Float16*)alloc((size_t)2 * 32768 * 2);
  P.amax = (unsigned long long*)alloc(32 * 8);
  if (off > ws_size) return;  // workspace too small: fail loudly via validation

  void* args[] = { &P };
  hipLaunchCooperativeKernel((void*)voice_coop, dim3(256), dim3(256), args, 0, stream);
}

// Round 3
// 19873.376 us; speedup vs baseline: 1.5354x; 1.5354x over previous
//
#include <hip/hip_runtime.h>
#include <hip/hip_cooperative_groups.h>
#include <cstdint>

namespace cg = cooperative_groups;

#define S_  128
#define Tt_ 64
#define V_  32000

typedef _Float16 h8 __attribute__((ext_vector_type(8)));
typedef float    f4 __attribute__((ext_vector_type(4)));

#define MFMA16(a,b,c) __builtin_amdgcn_mfma_f32_16x16x32_f16((a),(b),(c),0,0,0)

__device__ __forceinline__ void split8p(const float* __restrict__ p, h8& hi, h8& lo) {
  f4 a = *(const f4*)p;
  f4 b = *(const f4*)(p + 4);
#pragma unroll
  for (int i = 0; i < 4; i++) {
    _Float16 h0 = (_Float16)a[i];
    hi[i] = h0; lo[i] = (_Float16)((a[i] - (float)h0) * 2048.0f);
    _Float16 h1 = (_Float16)b[i];
    hi[i+4] = h1; lo[i+4] = (_Float16)((b[i] - (float)h1) * 2048.0f);
  }
}

// ============================ ENCODER (cooperative) ============================

struct EP {
  const int* itoks;
  const float* in_emb;
  const float* encWih; const float* encWhh; const float* encbih; const float* encbhh;
  float* out;
  _Float16 *seqH, *seqL;    // 129 slots x 32 x 1024
  _Float16 *he1H, *he1L;    // 2 slots
  _Float16 *hd0H, *hd0L;    // decoder l0 h slot0 gets final enc h
  _Float16 *hd1H, *hd1L;
  float *cb0, *cb1;         // decoder initial cell state
};

// LDS weight addressing: 16 rows x 2048 halves, XOR-swizzle 16B granules
__device__ __forceinline__ int wadr(int row, int k) {
  return row * 2048 + ((((k << 1) ^ ((row & 7) << 4))) >> 1);
}

__device__ void preload_enc(const float* __restrict__ Wih, const float* __restrict__ Whh,
                            int blk, int tid, _Float16* sWH, _Float16* sWL) {
#pragma unroll 4
  for (int it = 0; it < 32; ++it) {
    int lin = (it * 256 + tid) * 4;
    int j16 = lin >> 11;
    int k   = lin & 2047;
    int g = j16 >> 2, u = j16 & 3;
    int grow = g * 1024 + blk * 4 + u;
    const float* src = (k < 1024) ? (Wih + (size_t)grow * 1024 + k)
                                  : (Whh + (size_t)grow * 1024 + (k - 1024));
    f4 x = *(const f4*)src;
#pragma unroll
    for (int q = 0; q < 4; q++) {
      _Float16 hh = (_Float16)x[q];
      sWH[wadr(j16, k + q)] = hh;
      sWL[wadr(j16, k + q)] = (_Float16)((x[q] - (float)hh) * 2048.0f);
    }
  }
}

// XM: 1 = x gathered from in_emb[itoks[b,step]];  0 = x from split pair buffers
template <int XM>
__device__ void gates_enc(const _Float16* sWH, const _Float16* sWL, float* sScr,
                          const _Float16* __restrict__ xH, const _Float16* __restrict__ xL,
                          const float* __restrict__ emb, const int* __restrict__ itoks, int step,
                          const _Float16* __restrict__ hHb, const _Float16* __restrict__ hLb,
                          int tid) {
  int w = tid >> 6, lane = tid & 63;
  int kbase = w * 512;
  bool xp = (w < 2);
  int j16 = lane & 15;
  int tok0 = 0, tok1 = 0;
  if (XM == 1 && xp) {
    tok0 = itoks[(lane & 15) * S_ + step];
    tok1 = itoks[(16 + (lane & 15)) * S_ + step];
  }
  f4 accH[2] = {}, accM[2] = {};
  for (int ks = 0; ks < 16; ++ks) {
    int kk = kbase + ks * 32 + (lane >> 4) * 8;
    h8 Bh = *(const h8*)(sWH + wadr(j16, kk));
    h8 Bl = *(const h8*)(sWL + wadr(j16, kk));
#pragma unroll
    for (int mt = 0; mt < 2; ++mt) {
      int brow = mt * 16 + (lane & 15);
      h8 Ah, Al;
      if (xp) {
        if (XM == 1) {
          int tk = mt ? tok1 : tok0;
          split8p(emb + (size_t)tk * 1024 + kk, Ah, Al);
        } else {
          Ah = *(const h8*)(xH + (size_t)brow * 1024 + kk);
          Al = *(const h8*)(xL + (size_t)brow * 1024 + kk);
        }
      } else {
        Ah = *(const h8*)(hHb + (size_t)brow * 1024 + (kk - 1024));
        Al = *(const h8*)(hLb + (size_t)brow * 1024 + (kk - 1024));
      }
      accH[mt] = MFMA16(Ah, Bh, accH[mt]);
      accM[mt] = MFMA16(Ah, Bl, accM[mt]);
      accM[mt] = MFMA16(Al, Bh, accM[mt]);
    }
  }
#pragma unroll
  for (int mt = 0; mt < 2; ++mt)
#pragma unroll
    for (int r = 0; r < 4; ++r) {
      int b = mt * 16 + (lane >> 4) * 4 + r;
      sScr[w * 544 + b * 17 + j16] = accH[mt][r] + accM[mt][r] * (1.0f / 2048.0f);
    }
}

__device__ void finish_enc(float* sScr, int blk, int tid,
                           const float* __restrict__ bih, const float* __restrict__ bhh,
                           float& c,
                           _Float16* __restrict__ oH, _Float16* __restrict__ oL,
                           _Float16* __restrict__ oH2, _Float16* __restrict__ oL2,
                           float* __restrict__ cOut) {
  __syncthreads();
  if (tid < 128) {
    int u = tid >> 5, b = tid & 31;
    float g[4];
#pragma unroll
    for (int gg = 0; gg < 4; ++gg) {
      int j = gg * 4 + u;
      float s = sScr[0 * 544 + b * 17 + j] + sScr[1 * 544 + b * 17 + j]
              + sScr[2 * 544 + b * 17 + j] + sScr[3 * 544 + b * 17 + j];
      int grow = gg * 1024 + blk * 4 + u;
      g[gg] = s + bih[grow] + bhh[grow];
    }
    float ii = 1.0f / (1.0f + expf(-g[0]));
    float ff = 1.0f / (1.0f + expf(-g[1]));
    float gt = tanhf(g[2]);
    float oo = 1.0f / (1.0f + expf(-g[3]));
    c = ff * c + ii * gt;
    float hn = oo * tanhf(c);
    _Float16 hh = (_Float16)hn;
    _Float16 hl = (_Float16)((hn - (float)hh) * 2048.0f);
    int col = blk * 4 + u;
    size_t ci = (size_t)b * 1024 + col;
    oH[ci] = hh; oL[ci] = hl;
    if (oH2) { oH2[ci] = hh; oL2[ci] = hl; }
    if (cOut) cOut[ci] = c;
  }
  __syncthreads();
}

__global__ void __launch_bounds__(256, 1) voice_enc(EP P) {
  cg::grid_group grid = cg::this_grid();
  __shared__ _Float16 sWH[16 * 2048];
  __shared__ _Float16 sWL[16 * 2048];
  __shared__ float    sScr[4 * 544];
  int blk = blockIdx.x, tid = threadIdx.x;
  float cA = 0.0f, cB = 0.0f;

  // init: zero out[:,0,:], seq slot 0, he1 slot 0
  for (unsigned idx = blk * 256 + tid; idx < 32u * V_; idx += 65536u) {
    unsigned b = idx / V_, v = idx - b * V_;
    P.out[(size_t)b * (Tt_ * V_) + v] = 0.0f;
  }
  for (int idx = blk * 256 + tid; idx < 32 * 1024; idx += 65536) {
    P.seqH[idx] = (_Float16)0.0f; P.seqL[idx] = (_Float16)0.0f;
    P.he1H[idx] = (_Float16)0.0f; P.he1L[idx] = (_Float16)0.0f;
  }
  grid.sync();

  for (int l = 0; l < 2; ++l) {
    const float* Wih = P.encWih + (size_t)l * 4096 * 1024;
    const float* Whh = P.encWhh + (size_t)l * 4096 * 1024;
    const float* bih = P.encbih + (size_t)l * 4096;
    const float* bhh = P.encbhh + (size_t)l * 4096;
    preload_enc(Wih, Whh, blk, tid, sWH, sWL);
    grid.sync();
    for (int t = 0; t < 128; ++t) {
      bool last = (t == 127);
      if (l == 0) {
        gates_enc<1>(sWH, sWL, sScr, nullptr, nullptr, P.in_emb, P.itoks, t,
                     P.seqH + (size_t)t * 32768, P.seqL + (size_t)t * 32768, tid);
        finish_enc(sScr, blk, tid, bih, bhh, cA,
                   P.seqH + (size_t)(t + 1) * 32768, P.seqL + (size_t)(t + 1) * 32768,
                   last ? P.hd0H : nullptr, last ? P.hd0L : nullptr,
                   last ? P.cb0 : nullptr);
      } else {
        int pp = t & 1;
        gates_enc<0>(sWH, sWL, sScr,
                     P.seqH + (size_t)(t + 1) * 32768, P.seqL + (size_t)(t + 1) * 32768,
                     nullptr, nullptr, t,
                     P.he1H + (size_t)pp * 32768, P.he1L + (size_t)pp * 32768, tid);
        finish_enc(sScr, blk, tid, bih, bhh, cB,
                   P.he1H + (size_t)(pp ^ 1) * 32768, P.he1L + (size_t)(pp ^ 1) * 32768,
                   last ? P.hd1H : nullptr, last ? P.hd1L : nullptr,
                   last ? P.cb1 : nullptr);
      }
      grid.sync();
    }
  }
}

// ============================ DECODER (regular launches) ============================

// pre-split decoder weights into concat-K layout: dW[l][grow][k], k<1024 from Wih, else Whh
__global__ void k_split_dec(const float* __restrict__ decWih, const float* __restrict__ decWhh,
                            _Float16* __restrict__ WH, _Float16* __restrict__ WL) {
  int blk = blockIdx.x;               // 2*4096
  int tid = threadIdx.x;              // 256, 8 elems each
  int l = blk >> 12, grow = blk & 4095;
  int k = tid * 8;
  const float* src = (k < 1024) ? (decWih + ((size_t)l * 4096 + grow) * 1024 + k)
                                : (decWhh + ((size_t)l * 4096 + grow) * 1024 + (k - 1024));
  h8 hi, lo;
  split8p(src, hi, lo);
  size_t d = ((size_t)l * 4096 + grow) * 2048 + k;
  *(h8*)(WH + d) = hi;
  *(h8*)(WL + d) = lo;
}

// one decoder LSTM cell; 256 blocks x 512 threads; 8 K-sliced waves, LDS-reduce.
// XM: 2 = x from out_emb via token rule; 0 = x from split pair buffers.
template <int XM>
__global__ void __launch_bounds__(512, 1)
k_dcell(const _Float16* __restrict__ WH, const _Float16* __restrict__ WL,
        const float* __restrict__ bih, const float* __restrict__ bhh,
        const _Float16* __restrict__ xH, const _Float16* __restrict__ xL,
        const float* __restrict__ out_emb, const int* __restrict__ target,
        const int* __restrict__ tfm, unsigned long long* __restrict__ amax,
        const _Float16* __restrict__ hH, const _Float16* __restrict__ hL,
        _Float16* __restrict__ oH, _Float16* __restrict__ oL,
        float* __restrict__ cbuf, int step) {
  __shared__ float sScr[8 * 544];
  int tid = threadIdx.x, blk = blockIdx.x;
  if (XM == 0 && blk == 0 && tid < 32) amax[tid] = 0ull;   // reset for this step's proj
  int w = tid >> 6, lane = tid & 63;
  int j16 = lane & 15;
  int g_ = j16 >> 2, u_ = j16 & 3;
  int grow = g_ * 1024 + blk * 4 + u_;
  int kbase = w * 256;
  bool xp = (w < 4);

  int tok0 = 0, tok1 = 0;
  if (XM == 2 && xp) {
    int b0 = lane & 15, b1 = 16 + (lane & 15);
    if (step == 0)          { tok0 = target[b0 * Tt_];        tok1 = target[b1 * Tt_]; }
    else if (tfm[step] > 0) { tok0 = target[b0 * Tt_ + step]; tok1 = target[b1 * Tt_ + step]; }
    else { tok0 = (int)(~(unsigned)amax[b0]); tok1 = (int)(~(unsigned)amax[b1]); }
  }

  f4 accH[2] = {}, accM[2] = {};
  for (int ks = 0; ks < 8; ++ks) {
    int kk = kbase + ks * 32 + (lane >> 4) * 8;
    h8 Bh = *(const h8*)(WH + (size_t)grow * 2048 + kk);
    h8 Bl = *(const h8*)(WL + (size_t)grow * 2048 + kk);
#pragma unroll
    for (int mt = 0; mt < 2; ++mt) {
      int brow = mt * 16 + (lane & 15);
      h8 Ah, Al;
      if (xp) {
        if (XM == 2) {
          int tk = mt ? tok1 : tok0;
          split8p(out_emb + (size_t)tk * 1024 + kk, Ah, Al);
        } else {
          Ah = *(const h8*)(xH + (size_t)brow * 1024 + kk);
          Al = *(const h8*)(xL + (size_t)brow * 1024 + kk);
        }
      } else {
        Ah = *(const h8*)(hH + (size_t)brow * 1024 + (kk - 1024));
        Al = *(const h8*)(hL + (size_t)brow * 1024 + (kk - 1024));
      }
      accH[mt] = MFMA16(Ah, Bh, accH[mt]);
      accM[mt] = MFMA16(Ah, Bl, accM[mt]);
      accM[mt] = MFMA16(Al, Bh, accM[mt]);
    }
  }
#pragma unroll
  for (int mt = 0; mt < 2; ++mt)
#pragma unroll
    for (int r = 0; r < 4; ++r) {
      int b = mt * 16 + (lane >> 4) * 4 + r;
      sScr[w * 544 + b * 17 + j16] = accH[mt][r] + accM[mt][r] * (1.0f / 2048.0f);
    }
  __syncthreads();
  if (tid < 128) {
    int u = tid >> 5, b = tid & 31;
    float g[4];
#pragma unroll
    for (int gg = 0; gg < 4; ++gg) {
      int j = gg * 4 + u;
      float s = 0.0f;
#pragma unroll
      for (int ww = 0; ww < 8; ++ww) s += sScr[ww * 544 + b * 17 + j];
      int growf = gg * 1024 + blk * 4 + u;
      g[gg] = s + bih[growf] + bhh[growf];
    }
    float ii = 1.0f / (1.0f + expf(-g[0]));
    float ff = 1.0f / (1.0f + expf(-g[1]));
    float gt = tanhf(g[2]);
    float oo = 1.0f / (1.0f + expf(-g[3]));
    int col = blk * 4 + u;
    size_t ci = (size_t)b * 1024 + col;
    float cn = ff * cbuf[ci] + ii * gt;
    cbuf[ci] = cn;
    float hn = oo * tanhf(cn);
    _Float16 hh = (_Float16)hn;
    oH[ci] = hh;
    oL[ci] = (_Float16)((hn - (float)hh) * 2048.0f);
  }
}

// vocab projection: 2000 blocks x 64 threads; one wave covers 16 vcols x all 32 batches.
__global__ void __launch_bounds__(64, 1)
k_proj(const _Float16* __restrict__ hH, const _Float16* __restrict__ hL,
       const float* __restrict__ Wout, const float* __restrict__ bout,
       float* __restrict__ out, unsigned long long* __restrict__ amax, int step) {
  int lane = threadIdx.x;
  int vt = blockIdx.x;
  int vcol = vt * 16 + (lane & 15);
  int kof = (lane >> 4) * 8;
  const float* wrow = Wout + (size_t)vcol * 1024;
  f4 accH[2] = {}, accM[2] = {};
  for (int ks = 0; ks < 32; ++ks) {
    int kk = ks * 32 + kof;
    h8 Bh, Bl;
    split8p(wrow + kk, Bh, Bl);
#pragma unroll
    for (int mt = 0; mt < 2; ++mt) {
      int brow = mt * 16 + (lane & 15);
      h8 Ah = *(const h8*)(hH + (size_t)brow * 1024 + kk);
      h8 Al = *(const h8*)(hL + (size_t)brow * 1024 + kk);
      accH[mt] = MFMA16(Ah, Bh, accH[mt]);
      accM[mt] = MFMA16(Ah, Bl, accM[mt]);
      accM[mt] = MFMA16(Al, Bh, accM[mt]);
    }
  }
  float bias = bout[vcol];
#pragma unroll
  for (int mt = 0; mt < 2; ++mt) {
    float vr[4];
#pragma unroll
    for (int r = 0; r < 4; ++r) {
      int b = mt * 16 + (lane >> 4) * 4 + r;
      float v = accH[mt][r] + accM[mt][r] * (1.0f / 2048.0f) + bias;
      out[(size_t)b * (Tt_ * V_) + (size_t)(step + 1) * V_ + vcol] = v;
      vr[r] = v;
    }
#pragma unroll
    for (int r = 0; r < 4; ++r) {
      float v = vr[r];
      unsigned id = (unsigned)vcol;
#pragma unroll
      for (int off = 1; off < 16; off <<= 1) {
        float ov = __shfl_xor(v, off, 64);
        unsigned oi = __shfl_xor(id, off, 64);
        if (ov > v || (ov == v && oi < id)) { v = ov; id = oi; }
      }
      if ((lane & 15) == 0) {
        unsigned kb = __float_as_uint(v);
        kb = (kb & 0x80000000u) ? ~kb : (kb | 0x80000000u);
        unsigned long long key = ((unsigned long long)kb << 32) | (unsigned)(~id);
        int b = mt * 16 + (lane >> 4) * 4 + r;
        if (amax[b] < key) atomicMax(&amax[b], key);   // load-guard cuts contention
      }
    }
  }
}

// ============================ host ============================

extern "C" void kernel_launch(void* const* d_in, const int* in_sizes, int n_in,
                              void* d_out, int out_size, void* d_ws, size_t ws_size,
                              hipStream_t stream) {
  const int*   itoks   = (const int*)d_in[0];
  const int*   target  = (const int*)d_in[1];
  const int*   tfm     = (const int*)d_in[2];
  const float* in_emb  = (const float*)d_in[3];
  const float* out_emb = (const float*)d_in[4];
  const float* encWih  = (const float*)d_in[5];
  const float* encWhh  = (const float*)d_in[6];
  const float* encbih  = (const float*)d_in[7];
  const float* encbhh  = (const float*)d_in[8];
  const float* decWih  = (const float*)d_in[9];
  const float* decWhh  = (const float*)d_in[10];
  const float* decbih  = (const float*)d_in[11];
  const float* decbhh  = (const float*)d_in[12];
  const float* Wout    = (const float*)d_in[13];
  const float* bout    = (const float*)d_in[14];
  float* out = (float*)d_out;

  char* ws = (char*)d_ws;
  size_t off = 0;
  auto alloc = [&](size_t bytes) { void* p = ws + off; off += (bytes + 255) & ~(size_t)255; return p; };
  _Float16* seqH = (_Float16*)alloc((size_t)129 * 32768 * 2);
  _Float16* seqL = (_Float16*)alloc((size_t)129 * 32768 * 2);
  _Float16* he1H = (_Float16*)alloc((size_t)2 * 32768 * 2);
  _Float16* he1L = (_Float16*)alloc((size_t)2 * 32768 * 2);
  _Float16* hd0H = (_Float16*)alloc((size_t)2 * 32768 * 2);
  _Float16* hd0L = (_Float16*)alloc((size_t)2 * 32768 * 2);
  _Float16* hd1H = (_Float16*)alloc((size_t)2 * 32768 * 2);
  _Float16* hd1L = (_Float16*)alloc((size_t)2 * 32768 * 2);
  float*    cb0  = (float*)alloc((size_t)32 * 1024 * 4);
  float*    cb1  = (float*)alloc((size_t)32 * 1024 * 4);
  _Float16* dWH  = (_Float16*)alloc((size_t)2 * 4096 * 2048 * 2);
  _Float16* dWL  = (_Float16*)alloc((size_t)2 * 4096 * 2048 * 2);
  unsigned long long* amax = (unsigned long long*)alloc(32 * 8);
  if (off > ws_size) return;

  // 1) pre-split decoder weights
  k_split_dec<<<2 * 4096, 256, 0, stream>>>(decWih, decWhh, dWH, dWL);

  // 2) cooperative encoder
  EP P;
  P.itoks = itoks; P.in_emb = in_emb;
  P.encWih = encWih; P.encWhh = encWhh; P.encbih = encbih; P.encbhh = encbhh;
  P.out = out;
  P.seqH = seqH; P.seqL = seqL; P.he1H = he1H; P.he1L = he1L;
  P.hd0H = hd0H; P.hd0L = hd0L; P.hd1H = hd1H; P.hd1L = hd1L;
  P.cb0 = cb0; P.cb1 = cb1;
  void* args[] = { &P };
  hipLaunchCooperativeKernel((void*)voice_enc, dim3(256), dim3(256), args, 0, stream);

  // 3) decoder loop: 63 x (cell0, cell1, proj)
  const _Float16* WH0 = dWH;
  const _Float16* WL0 = dWL;
  const _Float16* WH1 = dWH + (size_t)4096 * 2048;
  const _Float16* WL1 = dWL + (size_t)4096 * 2048;
  for (int i = 0; i < 63; ++i) {
    int p = i & 1;
    _Float16* h0in  = hd0H + (size_t)p * 32768;        _Float16* h0inL = hd0L + (size_t)p * 32768;
    _Float16* h0out = hd0H + (size_t)(p ^ 1) * 32768;  _Float16* h0outL = hd0L + (size_t)(p ^ 1) * 32768;
    _Float16* h1in  = hd1H + (size_t)p * 32768;        _Float16* h1inL = hd1L + (size_t)p * 32768;
    _Float16* h1out = hd1H + (size_t)(p ^ 1) * 32768;  _Float16* h1outL = hd1L + (size_t)(p ^ 1) * 32768;

    k_dcell<2><<<256, 512, 0, stream>>>(WH0, WL0, decbih, decbhh,
                                        nullptr, nullptr, out_emb, target, tfm, amax,
                                        h0in, h0inL, h0out, h0outL, cb0, i);
    k_dcell<0><<<256, 512, 0, stream>>>(WH1, WL1, decbih + 4096, decbhh + 4096,
                                        h0out, h0outL, out_emb, target, tfm, amax,
                                        h1in, h1inL, h1out, h1outL, cb1, i);
    k_proj<<<2000, 64, 0, stream>>>(h1out, h1outL, Wout, bout, out, amax, i);
  }
}

// Round 4
// 15784.286 us; speedup vs baseline: 1.9332x; 1.2591x over previous
//
#include <hip/hip_runtime.h>
#include <cstdint>

#define S_  128
#define Tt_ 64
#define V_  32000
#define NB_ 256

typedef _Float16 h8 __attribute__((ext_vector_type(8)));
typedef float    f4 __attribute__((ext_vector_type(4)));

#define MFMA16(a,b,c) __builtin_amdgcn_mfma_f32_16x16x32_f16((a),(b),(c),0,0,0)

__device__ __forceinline__ void split8p(const float* __restrict__ p, h8& hi, h8& lo) {
  f4 a = *(const f4*)p;
  f4 b = *(const f4*)(p + 4);
#pragma unroll
  for (int i = 0; i < 4; i++) {
    _Float16 h0 = (_Float16)a[i];
    hi[i] = h0; lo[i] = (_Float16)((a[i] - (float)h0) * 2048.0f);
    _Float16 h1 = (_Float16)b[i];
    hi[i+4] = h1; lo[i+4] = (_Float16)((b[i] - (float)h1) * 2048.0f);
  }
}

// ---- fast device-wide barrier: per-block flag array + agent-scope fences ----
// flags: u32[NB_*4] (16B stride), zeroed before launch; target monotonically increases.
__device__ __forceinline__ void gsync(unsigned* flags, unsigned target) {
  __syncthreads();
  int tid = threadIdx.x;
  if (tid == 0) {
    __builtin_amdgcn_fence(__ATOMIC_RELEASE, "agent");
    __hip_atomic_store(&flags[blockIdx.x * 4], target, __ATOMIC_RELAXED,
                       __HIP_MEMORY_SCOPE_AGENT);
  }
  if (tid < 64) {
    bool done;
    do {
      unsigned m = 0xFFFFFFFFu;
#pragma unroll
      for (int q = 0; q < 4; ++q) {
        unsigned f = __hip_atomic_load(&flags[(tid + q * 64) * 4], __ATOMIC_RELAXED,
                                       __HIP_MEMORY_SCOPE_AGENT);
        m = m < f ? m : f;
      }
      done = (bool)__all(m >= target);
      if (!done) __builtin_amdgcn_s_sleep(1);
    } while (!done);
    __builtin_amdgcn_fence(__ATOMIC_ACQUIRE, "agent");
  }
  __syncthreads();
}

// ============================ prep kernels ============================

__global__ void k_init(unsigned* __restrict__ encF, unsigned* __restrict__ decF) {
  int i = threadIdx.x;
  for (int q = 0; q < 4; ++q) {
    int idx = q * 256 + i;
    if (idx < NB_ * 4) { encF[idx] = 0u; decF[idx] = 0u; }
  }
}

// dec weights -> split concat-K layout dW[l][grow][k] (k<1024: Wih, else Whh)
__global__ void k_split_dec(const float* __restrict__ decWih, const float* __restrict__ decWhh,
                            _Float16* __restrict__ WH, _Float16* __restrict__ WL) {
  int blk = blockIdx.x;               // 2*4096
  int tid = threadIdx.x;              // 256, 8 elems each
  int l = blk >> 12, grow = blk & 4095;
  int k = tid * 8;
  const float* src = (k < 1024) ? (decWih + ((size_t)l * 4096 + grow) * 1024 + k)
                                : (decWhh + ((size_t)l * 4096 + grow) * 1024 + (k - 1024));
  h8 hi, lo;
  split8p(src, hi, lo);
  size_t d = ((size_t)l * 4096 + grow) * 2048 + k;
  *(h8*)(WH + d) = hi;
  *(h8*)(WL + d) = lo;
}

// W_out -> split pair
__global__ void k_split_wout(const float* __restrict__ Wout,
                             _Float16* __restrict__ WoH, _Float16* __restrict__ WoL) {
  int row = blockIdx.x;               // 32000
  int k = threadIdx.x * 8;            // 128 thr
  h8 hi, lo;
  split8p(Wout + (size_t)row * 1024 + k, hi, lo);
  *(h8*)(WoH + (size_t)row * 1024 + k) = hi;
  *(h8*)(WoL + (size_t)row * 1024 + k) = lo;
}

// input embeddings gathered + split: emb[t][b][k], n = t*32+b
__global__ void k_emb(const int* __restrict__ itoks, const float* __restrict__ in_emb,
                      _Float16* __restrict__ embH, _Float16* __restrict__ embL) {
  int n = blockIdx.x;                 // 4096
  int b = n & 31, t = n >> 5;
  int tok = itoks[b * S_ + t];
  int k = threadIdx.x * 8;            // 128 thr
  h8 hi, lo;
  split8p(in_emb + (size_t)tok * 1024 + k, hi, lo);
  *(h8*)(embH + (size_t)n * 1024 + k) = hi;
  *(h8*)(embL + (size_t)n * 1024 + k) = lo;
}

// ============================ encoder (cooperative) ============================

struct EP {
  const float* encWih; const float* encWhh; const float* encbih; const float* encbhh;
  float* out;
  const _Float16 *embH, *embL;
  _Float16 *seqH, *seqL;    // 129 slots x 32 x 1024 (h history of layer0)
  _Float16 *he1H, *he1L;    // 2 parity slots
  _Float16 *hd0H, *hd0L;    // final enc h (decoder slot 0)
  _Float16 *hd1H, *hd1L;
  float *cb0, *cb1;
  unsigned* flags;
};

// LDS weight addressing: 16 rows x 2048 halves, XOR-swizzle 16B granules
__device__ __forceinline__ int wadr(int row, int k) {
  return row * 2048 + ((((k << 1) ^ ((row & 7) << 4))) >> 1);
}

__device__ void preload_enc(const float* __restrict__ Wih, const float* __restrict__ Whh,
                            int blk, int tid, _Float16* sWH, _Float16* sWL) {
#pragma unroll 4
  for (int it = 0; it < 32; ++it) {
    int lin = (it * 256 + tid) * 4;
    int j16 = lin >> 11;
    int k   = lin & 2047;
    int g = j16 >> 2, u = j16 & 3;
    int grow = g * 1024 + blk * 4 + u;
    const float* src = (k < 1024) ? (Wih + (size_t)grow * 1024 + k)
                                  : (Whh + (size_t)grow * 1024 + (k - 1024));
    f4 x = *(const f4*)src;
#pragma unroll
    for (int q = 0; q < 4; q++) {
      _Float16 hh = (_Float16)x[q];
      sWH[wadr(j16, k + q)] = hh;
      sWL[wadr(j16, k + q)] = (_Float16)((x[q] - (float)hh) * 2048.0f);
    }
  }
}

__device__ void gates_enc(const _Float16* sWH, const _Float16* sWL, float* sScr,
                          const _Float16* __restrict__ xH, const _Float16* __restrict__ xL,
                          const _Float16* __restrict__ hHb, const _Float16* __restrict__ hLb,
                          int tid) {
  int w = tid >> 6, lane = tid & 63;
  int kbase = w * 512;
  bool xp = (w < 2);
  int j16 = lane & 15;
  const _Float16* aH = xp ? xH : (hHb - 1024);
  const _Float16* aL = xp ? xL : (hLb - 1024);
  f4 accH[2] = {}, accM[2] = {};
  for (int ks = 0; ks < 16; ++ks) {
    int kk = kbase + ks * 32 + (lane >> 4) * 8;
    h8 Bh = *(const h8*)(sWH + wadr(j16, kk));
    h8 Bl = *(const h8*)(sWL + wadr(j16, kk));
#pragma unroll
    for (int mt = 0; mt < 2; ++mt) {
      int brow = mt * 16 + (lane & 15);
      h8 Ah = *(const h8*)(aH + (size_t)brow * 1024 + kk);
      h8 Al = *(const h8*)(aL + (size_t)brow * 1024 + kk);
      accH[mt] = MFMA16(Ah, Bh, accH[mt]);
      accM[mt] = MFMA16(Ah, Bl, accM[mt]);
      accM[mt] = MFMA16(Al, Bh, accM[mt]);
    }
  }
#pragma unroll
  for (int mt = 0; mt < 2; ++mt)
#pragma unroll
    for (int r = 0; r < 4; ++r) {
      int b = mt * 16 + (lane >> 4) * 4 + r;
      sScr[w * 544 + b * 17 + j16] = accH[mt][r] + accM[mt][r] * (1.0f / 2048.0f);
    }
}

__device__ void finish_enc(float* sScr, int blk, int tid,
                           const float* __restrict__ bih, const float* __restrict__ bhh,
                           float& c,
                           _Float16* __restrict__ oH, _Float16* __restrict__ oL,
                           _Float16* __restrict__ oH2, _Float16* __restrict__ oL2,
                           float* __restrict__ cOut) {
  __syncthreads();
  if (tid < 128) {
    int u = tid >> 5, b = tid & 31;
    float g[4];
#pragma unroll
    for (int gg = 0; gg < 4; ++gg) {
      int j = gg * 4 + u;
      float s = sScr[0 * 544 + b * 17 + j] + sScr[1 * 544 + b * 17 + j]
              + sScr[2 * 544 + b * 17 + j] + sScr[3 * 544 + b * 17 + j];
      int grow = gg * 1024 + blk * 4 + u;
      g[gg] = s + bih[grow] + bhh[grow];
    }
    float ii = 1.0f / (1.0f + expf(-g[0]));
    float ff = 1.0f / (1.0f + expf(-g[1]));
    float gt = tanhf(g[2]);
    float oo = 1.0f / (1.0f + expf(-g[3]));
    c = ff * c + ii * gt;
    float hn = oo * tanhf(c);
    _Float16 hh = (_Float16)hn;
    _Float16 hl = (_Float16)((hn - (float)hh) * 2048.0f);
    int col = blk * 4 + u;
    size_t ci = (size_t)b * 1024 + col;
    oH[ci] = hh; oL[ci] = hl;
    if (oH2) { oH2[ci] = hh; oL2[ci] = hl; }
    if (cOut) cOut[ci] = c;
  }
}

__global__ void __launch_bounds__(256, 1) voice_enc(EP P) {
  __shared__ _Float16 sWH[16 * 2048];
  __shared__ _Float16 sWL[16 * 2048];
  __shared__ float    sScr[4 * 544];
  int blk = blockIdx.x, tid = threadIdx.x;
  float cA = 0.0f, cB = 0.0f;
  unsigned ep = 0;

  // init: zero out[:,0,:], seq slot 0, he1 slot 0
  for (unsigned idx = blk * 256 + tid; idx < 32u * V_; idx += 65536u) {
    unsigned b = idx / V_, v = idx - b * V_;
    P.out[(size_t)b * (Tt_ * V_) + v] = 0.0f;
  }
  for (int idx = blk * 256 + tid; idx < 32 * 1024; idx += 65536) {
    P.seqH[idx] = (_Float16)0.0f; P.seqL[idx] = (_Float16)0.0f;
    P.he1H[idx] = (_Float16)0.0f; P.he1L[idx] = (_Float16)0.0f;
  }
  gsync(P.flags, ++ep * NB_);

  for (int l = 0; l < 2; ++l) {
    const float* Wih = P.encWih + (size_t)l * 4096 * 1024;
    const float* Whh = P.encWhh + (size_t)l * 4096 * 1024;
    const float* bih = P.encbih + (size_t)l * 4096;
    const float* bhh = P.encbhh + (size_t)l * 4096;
    preload_enc(Wih, Whh, blk, tid, sWH, sWL);
    __syncthreads();
    for (int t = 0; t < 128; ++t) {
      bool last = (t == 127);
      if (l == 0) {
        gates_enc(sWH, sWL, sScr,
                  P.embH + (size_t)t * 32768, P.embL + (size_t)t * 32768,
                  P.seqH + (size_t)t * 32768, P.seqL + (size_t)t * 32768, tid);
        finish_enc(sScr, blk, tid, bih, bhh, cA,
                   P.seqH + (size_t)(t + 1) * 32768, P.seqL + (size_t)(t + 1) * 32768,
                   last ? P.hd0H : nullptr, last ? P.hd0L : nullptr,
                   last ? P.cb0 : nullptr);
      } else {
        int pp = t & 1;
        gates_enc(sWH, sWL, sScr,
                  P.seqH + (size_t)(t + 1) * 32768, P.seqL + (size_t)(t + 1) * 32768,
                  P.he1H + (size_t)pp * 32768, P.he1L + (size_t)pp * 32768, tid);
        finish_enc(sScr, blk, tid, bih, bhh, cB,
                   P.he1H + (size_t)(pp ^ 1) * 32768, P.he1L + (size_t)(pp ^ 1) * 32768,
                   last ? P.hd1H : nullptr, last ? P.hd1L : nullptr,
                   last ? P.cb1 : nullptr);
      }
      gsync(P.flags, ++ep * NB_);
    }
  }
}

// ============================ decoder (cooperative persistent) ============================

struct DP {
  const float* out_emb; const int* target; const int* tfm;
  const _Float16 *dWH, *dWL;        // [2][4096][2048]
  const float *decbih, *decbhh;     // [2][4096]
  const _Float16 *WoH, *WoL;        // [32000][1024]
  const float* bout;
  float* out;
  _Float16 *hd0H, *hd0L, *hd1H, *hd1L;  // 2 parity slots each
  const float *cb0, *cb1;
  unsigned long long* amax;
  unsigned* flags;
};

// one LSTM cell phase on 512 threads (8 waves, K=2048 split 256/wave).
// XM: 2 = x gathered from out_emb via token rule; 0 = x from split pair.
template <int XM>
__device__ void dcell(const _Float16* __restrict__ WH, const _Float16* __restrict__ WL,
                      const float* __restrict__ bih, const float* __restrict__ bhh,
                      const _Float16* __restrict__ xH, const _Float16* __restrict__ xL,
                      const float* __restrict__ out_emb, const int* __restrict__ target,
                      const int* __restrict__ tfm, const unsigned long long* __restrict__ amax,
                      const _Float16* __restrict__ hH, const _Float16* __restrict__ hL,
                      _Float16* __restrict__ oH, _Float16* __restrict__ oL,
                      float& c, int step, float* sScr, int blk, int tid) {
  int w = tid >> 6, lane = tid & 63;
  int j16 = lane & 15;
  int g_ = j16 >> 2, u_ = j16 & 3;
  int grow = g_ * 1024 + blk * 4 + u_;
  int kbase = w * 256;
  bool xp = (w < 4);

  int tok0 = 0, tok1 = 0;
  if (XM == 2 && xp) {
    int b0 = lane & 15, b1 = 16 + (lane & 15);
    if (step == 0)          { tok0 = target[b0 * Tt_];        tok1 = target[b1 * Tt_]; }
    else if (tfm[step] > 0) { tok0 = target[b0 * Tt_ + step]; tok1 = target[b1 * Tt_ + step]; }
    else { tok0 = (int)(~(unsigned)amax[b0]); tok1 = (int)(~(unsigned)amax[b1]); }
  }
  const _Float16* aH = xp ? xH : (hH - 1024);
  const _Float16* aL = xp ? xL : (hL - 1024);

  f4 accH[2] = {}, accM[2] = {};
  for (int ks = 0; ks < 8; ++ks) {
    int kk = kbase + ks * 32 + (lane >> 4) * 8;
    h8 Bh = *(const h8*)(WH + (size_t)grow * 2048 + kk);
    h8 Bl = *(const h8*)(WL + (size_t)grow * 2048 + kk);
#pragma unroll
    for (int mt = 0; mt < 2; ++mt) {
      int brow = mt * 16 + (lane & 15);
      h8 Ah, Al;
      if (XM == 2 && xp) {
        int tk = mt ? tok1 : tok0;
        split8p(out_emb + (size_t)tk * 1024 + kk, Ah, Al);
      } else {
        Ah = *(const h8*)(aH + (size_t)brow * 1024 + kk);
        Al = *(const h8*)(aL + (size_t)brow * 1024 + kk);
      }
      accH[mt] = MFMA16(Ah, Bh, accH[mt]);
      accM[mt] = MFMA16(Ah, Bl, accM[mt]);
      accM[mt] = MFMA16(Al, Bh, accM[mt]);
    }
  }
#pragma unroll
  for (int mt = 0; mt < 2; ++mt)
#pragma unroll
    for (int r = 0; r < 4; ++r) {
      int b = mt * 16 + (lane >> 4) * 4 + r;
      sScr[w * 544 + b * 17 + j16] = accH[mt][r] + accM[mt][r] * (1.0f / 2048.0f);
    }
  __syncthreads();
  if (tid < 128) {
    int u = tid >> 5, b = tid & 31;
    float g[4];
#pragma unroll
    for (int gg = 0; gg < 4; ++gg) {
      int j = gg * 4 + u;
      float s = 0.0f;
#pragma unroll
      for (int ww = 0; ww < 8; ++ww) s += sScr[ww * 544 + b * 17 + j];
      int growf = gg * 1024 + blk * 4 + u;
      g[gg] = s + bih[growf] + bhh[growf];
    }
    float ii = 1.0f / (1.0f + expf(-g[0]));
    float ff = 1.0f / (1.0f + expf(-g[1]));
    float gt = tanhf(g[2]);
    float oo = 1.0f / (1.0f + expf(-g[3]));
    c = ff * c + ii * gt;
    float hn = oo * tanhf(c);
    _Float16 hh = (_Float16)hn;
    int col = blk * 4 + u;
    size_t ci = (size_t)b * 1024 + col;
    oH[ci] = hh;
    oL[ci] = (_Float16)((hn - (float)hh) * 2048.0f);
  }
}

__global__ void __launch_bounds__(512, 2) voice_dec(DP P) {
  __shared__ float sScr[8 * 544];
  int blk = blockIdx.x, tid = threadIdx.x;
  unsigned ep = 0;
  float c0 = 0.0f, c1 = 0.0f;
  if (tid < 128) {
    int u = tid >> 5, b = tid & 31;
    size_t ci = (size_t)b * 1024 + blk * 4 + u;
    c0 = P.cb0[ci];
    c1 = P.cb1[ci];
  }

  for (int i = 0; i < 63; ++i) {
    int p = i & 1;
    _Float16* h0in  = P.hd0H + (size_t)p * 32768;        _Float16* h0inL  = P.hd0L + (size_t)p * 32768;
    _Float16* h0out = P.hd0H + (size_t)(p ^ 1) * 32768;  _Float16* h0outL = P.hd0L + (size_t)(p ^ 1) * 32768;
    _Float16* h1in  = P.hd1H + (size_t)p * 32768;        _Float16* h1inL  = P.hd1L + (size_t)p * 32768;
    _Float16* h1out = P.hd1H + (size_t)(p ^ 1) * 32768;  _Float16* h1outL = P.hd1L + (size_t)(p ^ 1) * 32768;

    // phase A: layer0 cell (token-rule x)
    dcell<2>(P.dWH, P.dWL, P.decbih, P.decbhh,
             nullptr, nullptr, P.out_emb, P.target, P.tfm, P.amax,
             h0in, h0inL, h0out, h0outL, c0, i, sScr, blk, tid);
    gsync(P.flags, ++ep * NB_);

    // phase B: layer1 cell; also reset amax for this step's proj
    if (blk == 0 && tid < 32) P.amax[tid] = 0ull;
    dcell<0>(P.dWH + (size_t)4096 * 2048, P.dWL + (size_t)4096 * 2048,
             P.decbih + 4096, P.decbhh + 4096,
             h0out, h0outL, nullptr, nullptr, nullptr, nullptr,
             h1in, h1inL, h1out, h1outL, c1, i, sScr, blk, tid);
    gsync(P.flags, ++ep * NB_);

    // phase C: vocab projection + out write + argmax
    {
      int w = tid >> 6, lane = tid & 63;
      int vt = blk * 8 + w;
      if (vt < 2000) {
        int vcol = vt * 16 + (lane & 15);
        int kof = (lane >> 4) * 8;
        f4 accH[2] = {}, accM[2] = {};
        for (int ks = 0; ks < 32; ++ks) {
          int kk = ks * 32 + kof;
          h8 Bh = *(const h8*)(P.WoH + (size_t)vcol * 1024 + kk);
          h8 Bl = *(const h8*)(P.WoL + (size_t)vcol * 1024 + kk);
#pragma unroll
          for (int mt = 0; mt < 2; ++mt) {
            int brow = mt * 16 + (lane & 15);
            h8 Ah = *(const h8*)(h1out  + (size_t)brow * 1024 + kk);
            h8 Al = *(const h8*)(h1outL + (size_t)brow * 1024 + kk);
            accH[mt] = MFMA16(Ah, Bh, accH[mt]);
            accM[mt] = MFMA16(Ah, Bl, accM[mt]);
            accM[mt] = MFMA16(Al, Bh, accM[mt]);
          }
        }
        float bias = P.bout[vcol];
#pragma unroll
        for (int mt = 0; mt < 2; ++mt) {
          float vr[4];
#pragma unroll
          for (int r = 0; r < 4; ++r) {
            int b = mt * 16 + (lane >> 4) * 4 + r;
            float v = accH[mt][r] + accM[mt][r] * (1.0f / 2048.0f) + bias;
            P.out[(size_t)b * (Tt_ * V_) + (size_t)(i + 1) * V_ + vcol] = v;
            vr[r] = v;
          }
#pragma unroll
          for (int r = 0; r < 4; ++r) {
            float v = vr[r];
            unsigned id = (unsigned)vcol;
#pragma unroll
            for (int off = 1; off < 16; off <<= 1) {
              float ov = __shfl_xor(v, off, 64);
              unsigned oi = __shfl_xor(id, off, 64);
              if (ov > v || (ov == v && oi < id)) { v = ov; id = oi; }
            }
            if ((lane & 15) == 0) {
              unsigned kb = __float_as_uint(v);
              kb = (kb & 0x80000000u) ? ~kb : (kb | 0x80000000u);
              unsigned long long key = ((unsigned long long)kb << 32) | (unsigned)(~id);
              int b = mt * 16 + (lane >> 4) * 4 + r;
              if (P.amax[b] < key) atomicMax(&P.amax[b], key);
            }
          }
        }
      }
    }
    gsync(P.flags, ++ep * NB_);
  }
}

// ============================ host ============================

extern "C" void kernel_launch(void* const* d_in, const int* in_sizes, int n_in,
                              void* d_out, int out_size, void* d_ws, size_t ws_size,
                              hipStream_t stream) {
  const int*   itoks   = (const int*)d_in[0];
  const int*   target  = (const int*)d_in[1];
  const int*   tfm     = (const int*)d_in[2];
  const float* in_emb  = (const float*)d_in[3];
  const float* out_emb = (const float*)d_in[4];
  const float* encWih  = (const float*)d_in[5];
  const float* encWhh  = (const float*)d_in[6];
  const float* encbih  = (const float*)d_in[7];
  const float* encbhh  = (const float*)d_in[8];
  const float* decWih  = (const float*)d_in[9];
  const float* decWhh  = (const float*)d_in[10];
  const float* decbih  = (const float*)d_in[11];
  const float* decbhh  = (const float*)d_in[12];
  const float* Wout    = (const float*)d_in[13];
  const float* bout    = (const float*)d_in[14];
  float* out = (float*)d_out;

  char* ws = (char*)d_ws;
  size_t off = 0;
  auto alloc = [&](size_t bytes) { void* p = ws + off; off += (bytes + 255) & ~(size_t)255; return p; };
  _Float16* seqH = (_Float16*)alloc((size_t)129 * 32768 * 2);
  _Float16* seqL = (_Float16*)alloc((size_t)129 * 32768 * 2);
  _Float16* embH = (_Float16*)alloc((size_t)128 * 32768 * 2);
  _Float16* embL = (_Float16*)alloc((size_t)128 * 32768 * 2);
  _Float16* he1H = (_Float16*)alloc((size_t)2 * 32768 * 2);
  _Float16* he1L = (_Float16*)alloc((size_t)2 * 32768 * 2);
  _Float16* hd0H = (_Float16*)alloc((size_t)2 * 32768 * 2);
  _Float16* hd0L = (_Float16*)alloc((size_t)2 * 32768 * 2);
  _Float16* hd1H = (_Float16*)alloc((size_t)2 * 32768 * 2);
  _Float16* hd1L = (_Float16*)alloc((size_t)2 * 32768 * 2);
  float*    cb0  = (float*)alloc((size_t)32 * 1024 * 4);
  float*    cb1  = (float*)alloc((size_t)32 * 1024 * 4);
  _Float16* dWH  = (_Float16*)alloc((size_t)2 * 4096 * 2048 * 2);
  _Float16* dWL  = (_Float16*)alloc((size_t)2 * 4096 * 2048 * 2);
  _Float16* WoH  = (_Float16*)alloc((size_t)32000 * 1024 * 2);
  _Float16* WoL  = (_Float16*)alloc((size_t)32000 * 1024 * 2);
  unsigned long long* amax = (unsigned long long*)alloc(32 * 8);
  unsigned* encF = (unsigned*)alloc(NB_ * 4 * 4);
  unsigned* decF = (unsigned*)alloc(NB_ * 4 * 4);
  if (off > ws_size) return;

  // prep
  k_init<<<1, 256, 0, stream>>>(encF, decF);
  k_split_dec<<<2 * 4096, 256, 0, stream>>>(decWih, decWhh, dWH, dWL);
  k_split_wout<<<32000, 128, 0, stream>>>(Wout, WoH, WoL);
  k_emb<<<4096, 128, 0, stream>>>(itoks, in_emb, embH, embL);

  // encoder (cooperative for guaranteed co-residency; own barrier inside)
  EP E;
  E.encWih = encWih; E.encWhh = encWhh; E.encbih = encbih; E.encbhh = encbhh;
  E.out = out; E.embH = embH; E.embL = embL;
  E.seqH = seqH; E.seqL = seqL; E.he1H = he1H; E.he1L = he1L;
  E.hd0H = hd0H; E.hd0L = hd0L; E.hd1H = hd1H; E.hd1L = hd1L;
  E.cb0 = cb0; E.cb1 = cb1; E.flags = encF;
  void* eargs[] = { &E };
  hipLaunchCooperativeKernel((void*)voice_enc, dim3(NB_), dim3(256), eargs, 0, stream);

  // decoder (cooperative persistent)
  DP D;
  D.out_emb = out_emb; D.target = target; D.tfm = tfm;
  D.dWH = dWH; D.dWL = dWL; D.decbih = decbih; D.decbhh = decbhh;
  D.WoH = WoH; D.WoL = WoL; D.bout = bout; D.out = out;
  D.hd0H = hd0H; D.hd0L = hd0L; D.hd1H = hd1H; D.hd1L = hd1L;
  D.cb0 = cb0; D.cb1 = cb1; D.amax = amax; D.flags = decF;
  void* dargs[] = { &D };
  hipLaunchCooperativeKernel((void*)voice_dec, dim3(NB_), dim3(512), dargs, 0, stream);
}

// Round 5
// 13764.494 us; speedup vs baseline: 2.2168x; 1.1467x over previous
//
#include <hip/hip_runtime.h>
#include <cstdint>

#define S_  128
#define Tt_ 64
#define V_  32000
#define NB_ 256

typedef _Float16 h8 __attribute__((ext_vector_type(8)));
typedef float    f4 __attribute__((ext_vector_type(4)));

#define MFMA16(a,b,c) __builtin_amdgcn_mfma_f32_16x16x32_f16((a),(b),(c),0,0,0)

__device__ __forceinline__ void split8p(const float* __restrict__ p, h8& hi, h8& lo) {
  f4 a = *(const f4*)p;
  f4 b = *(const f4*)(p + 4);
#pragma unroll
  for (int i = 0; i < 4; i++) {
    _Float16 h0 = (_Float16)a[i];
    hi[i] = h0; lo[i] = (_Float16)((a[i] - (float)h0) * 2048.0f);
    _Float16 h1 = (_Float16)b[i];
    hi[i+4] = h1; lo[i+4] = (_Float16)((b[i] - (float)h1) * 2048.0f);
  }
}

// ---- fast device-wide barrier: per-block flag array + agent-scope fences ----
__device__ __forceinline__ void gsync(unsigned* flags, unsigned target) {
  __syncthreads();
  int tid = threadIdx.x;
  if (tid == 0) {
    __builtin_amdgcn_fence(__ATOMIC_RELEASE, "agent");
    __hip_atomic_store(&flags[blockIdx.x * 4], target, __ATOMIC_RELAXED,
                       __HIP_MEMORY_SCOPE_AGENT);
  }
  if (tid < 64) {
    bool done;
    do {
      unsigned m = 0xFFFFFFFFu;
#pragma unroll
      for (int q = 0; q < 4; ++q) {
        unsigned f = __hip_atomic_load(&flags[(tid + q * 64) * 4], __ATOMIC_RELAXED,
                                       __HIP_MEMORY_SCOPE_AGENT);
        m = m < f ? m : f;
      }
      done = (bool)__all(m >= target);
      if (!done) __builtin_amdgcn_s_sleep(1);
    } while (!done);
    __builtin_amdgcn_fence(__ATOMIC_ACQUIRE, "agent");
  }
  __syncthreads();
}

// ============================ prep kernels ============================

__global__ void k_init(unsigned* __restrict__ encF, unsigned* __restrict__ decF) {
  int i = threadIdx.x;
  for (int q = 0; q < 4; ++q) {
    int idx = q * 256 + i;
    if (idx < NB_ * 4) { encF[idx] = 0u; decF[idx] = 0u; }
  }
}

__global__ void k_split_dec(const float* __restrict__ decWih, const float* __restrict__ decWhh,
                            _Float16* __restrict__ WH, _Float16* __restrict__ WL) {
  int blk = blockIdx.x;               // 2*4096
  int tid = threadIdx.x;              // 256
  int l = blk >> 12, grow = blk & 4095;
  int k = tid * 8;
  const float* src = (k < 1024) ? (decWih + ((size_t)l * 4096 + grow) * 1024 + k)
                                : (decWhh + ((size_t)l * 4096 + grow) * 1024 + (k - 1024));
  h8 hi, lo;
  split8p(src, hi, lo);
  size_t d = ((size_t)l * 4096 + grow) * 2048 + k;
  *(h8*)(WH + d) = hi;
  *(h8*)(WL + d) = lo;
}

__global__ void k_split_wout(const float* __restrict__ Wout,
                             _Float16* __restrict__ WoH, _Float16* __restrict__ WoL) {
  int row = blockIdx.x;               // 32000
  int k = threadIdx.x * 8;            // 128 thr
  h8 hi, lo;
  split8p(Wout + (size_t)row * 1024 + k, hi, lo);
  *(h8*)(WoH + (size_t)row * 1024 + k) = hi;
  *(h8*)(WoL + (size_t)row * 1024 + k) = lo;
}

__global__ void k_emb(const int* __restrict__ itoks, const float* __restrict__ in_emb,
                      _Float16* __restrict__ embH, _Float16* __restrict__ embL) {
  int n = blockIdx.x;                 // 4096
  int b = n & 31, t = n >> 5;
  int tok = itoks[b * S_ + t];
  int k = threadIdx.x * 8;            // 128 thr
  h8 hi, lo;
  split8p(in_emb + (size_t)tok * 1024 + k, hi, lo);
  *(h8*)(embH + (size_t)n * 1024 + k) = hi;
  *(h8*)(embL + (size_t)n * 1024 + k) = lo;
}

// ============================ encoder (cooperative) ============================

struct EP {
  const float* encWih; const float* encWhh; const float* encbih; const float* encbhh;
  float* out;
  const _Float16 *embH, *embL;
  _Float16 *seqH, *seqL;
  _Float16 *he1H, *he1L;
  _Float16 *hd0H, *hd0L;
  _Float16 *h1s0H, *h1s0L;   // hist slot 0
  float *cb0, *cb1;
  unsigned* flags;
};

__device__ __forceinline__ int wadr(int row, int k) {
  return row * 2048 + ((((k << 1) ^ ((row & 7) << 4))) >> 1);
}

__device__ void preload_enc(const float* __restrict__ Wih, const float* __restrict__ Whh,
                            int blk, int tid, _Float16* sWH, _Float16* sWL) {
#pragma unroll 4
  for (int it = 0; it < 32; ++it) {
    int lin = (it * 256 + tid) * 4;
    int j16 = lin >> 11;
    int k   = lin & 2047;
    int g = j16 >> 2, u = j16 & 3;
    int grow = g * 1024 + blk * 4 + u;
    const float* src = (k < 1024) ? (Wih + (size_t)grow * 1024 + k)
                                  : (Whh + (size_t)grow * 1024 + (k - 1024));
    f4 x = *(const f4*)src;
#pragma unroll
    for (int q = 0; q < 4; q++) {
      _Float16 hh = (_Float16)x[q];
      sWH[wadr(j16, k + q)] = hh;
      sWL[wadr(j16, k + q)] = (_Float16)((x[q] - (float)hh) * 2048.0f);
    }
  }
}

__device__ void gates_enc(const _Float16* sWH, const _Float16* sWL, float* sScr,
                          const _Float16* __restrict__ xH, const _Float16* __restrict__ xL,
                          const _Float16* __restrict__ hHb, const _Float16* __restrict__ hLb,
                          int tid) {
  int w = tid >> 6, lane = tid & 63;
  int kbase = w * 512;
  bool xp = (w < 2);
  int j16 = lane & 15;
  const _Float16* aH = xp ? xH : (hHb - 1024);
  const _Float16* aL = xp ? xL : (hLb - 1024);
  f4 accH[2] = {}, accM[2] = {};
  for (int ks = 0; ks < 16; ++ks) {
    int kk = kbase + ks * 32 + (lane >> 4) * 8;
    h8 Bh = *(const h8*)(sWH + wadr(j16, kk));
    h8 Bl = *(const h8*)(sWL + wadr(j16, kk));
#pragma unroll
    for (int mt = 0; mt < 2; ++mt) {
      int brow = mt * 16 + (lane & 15);
      h8 Ah = *(const h8*)(aH + (size_t)brow * 1024 + kk);
      h8 Al = *(const h8*)(aL + (size_t)brow * 1024 + kk);
      accH[mt] = MFMA16(Ah, Bh, accH[mt]);
      accM[mt] = MFMA16(Ah, Bl, accM[mt]);
      accM[mt] = MFMA16(Al, Bh, accM[mt]);
    }
  }
#pragma unroll
  for (int mt = 0; mt < 2; ++mt)
#pragma unroll
    for (int r = 0; r < 4; ++r) {
      int b = mt * 16 + (lane >> 4) * 4 + r;
      sScr[w * 544 + b * 17 + j16] = accH[mt][r] + accM[mt][r] * (1.0f / 2048.0f);
    }
}

__device__ void finish_enc(float* sScr, int blk, int tid,
                           const float* __restrict__ bih, const float* __restrict__ bhh,
                           float& c,
                           _Float16* __restrict__ oH, _Float16* __restrict__ oL,
                           _Float16* __restrict__ oH2, _Float16* __restrict__ oL2,
                           float* __restrict__ cOut) {
  __syncthreads();
  if (tid < 128) {
    int u = tid >> 5, b = tid & 31;
    float g[4];
#pragma unroll
    for (int gg = 0; gg < 4; ++gg) {
      int j = gg * 4 + u;
      float s = sScr[0 * 544 + b * 17 + j] + sScr[1 * 544 + b * 17 + j]
              + sScr[2 * 544 + b * 17 + j] + sScr[3 * 544 + b * 17 + j];
      int grow = gg * 1024 + blk * 4 + u;
      g[gg] = s + bih[grow] + bhh[grow];
    }
    float ii = 1.0f / (1.0f + expf(-g[0]));
    float ff = 1.0f / (1.0f + expf(-g[1]));
    float gt = tanhf(g[2]);
    float oo = 1.0f / (1.0f + expf(-g[3]));
    c = ff * c + ii * gt;
    float hn = oo * tanhf(c);
    _Float16 hh = (_Float16)hn;
    _Float16 hl = (_Float16)((hn - (float)hh) * 2048.0f);
    int col = blk * 4 + u;
    size_t ci = (size_t)b * 1024 + col;
    oH[ci] = hh; oL[ci] = hl;
    if (oH2) { oH2[ci] = hh; oL2[ci] = hl; }
    if (cOut) cOut[ci] = c;
  }
}

__global__ void __launch_bounds__(256, 1) voice_enc(EP P) {
  __shared__ _Float16 sWH[16 * 2048];
  __shared__ _Float16 sWL[16 * 2048];
  __shared__ float    sScr[4 * 544];
  int blk = blockIdx.x, tid = threadIdx.x;
  float cA = 0.0f, cB = 0.0f;
  unsigned ep = 0;

  for (unsigned idx = blk * 256 + tid; idx < 32u * V_; idx += 65536u) {
    unsigned b = idx / V_, v = idx - b * V_;
    P.out[(size_t)b * (Tt_ * V_) + v] = 0.0f;
  }
  for (int idx = blk * 256 + tid; idx < 32 * 1024; idx += 65536) {
    P.seqH[idx] = (_Float16)0.0f; P.seqL[idx] = (_Float16)0.0f;
    P.he1H[idx] = (_Float16)0.0f; P.he1L[idx] = (_Float16)0.0f;
  }
  gsync(P.flags, ++ep * NB_);

  for (int l = 0; l < 2; ++l) {
    const float* Wih = P.encWih + (size_t)l * 4096 * 1024;
    const float* Whh = P.encWhh + (size_t)l * 4096 * 1024;
    const float* bih = P.encbih + (size_t)l * 4096;
    const float* bhh = P.encbhh + (size_t)l * 4096;
    preload_enc(Wih, Whh, blk, tid, sWH, sWL);
    __syncthreads();
    for (int t = 0; t < 128; ++t) {
      bool last = (t == 127);
      if (l == 0) {
        gates_enc(sWH, sWL, sScr,
                  P.embH + (size_t)t * 32768, P.embL + (size_t)t * 32768,
                  P.seqH + (size_t)t * 32768, P.seqL + (size_t)t * 32768, tid);
        finish_enc(sScr, blk, tid, bih, bhh, cA,
                   P.seqH + (size_t)(t + 1) * 32768, P.seqL + (size_t)(t + 1) * 32768,
                   last ? P.hd0H : nullptr, last ? P.hd0L : nullptr,
                   last ? P.cb0 : nullptr);
      } else {
        int pp = t & 1;
        gates_enc(sWH, sWL, sScr,
                  P.seqH + (size_t)(t + 1) * 32768, P.seqL + (size_t)(t + 1) * 32768,
                  P.he1H + (size_t)pp * 32768, P.he1L + (size_t)pp * 32768, tid);
        finish_enc(sScr, blk, tid, bih, bhh, cB,
                   P.he1H + (size_t)(pp ^ 1) * 32768, P.he1L + (size_t)(pp ^ 1) * 32768,
                   last ? P.h1s0H : nullptr, last ? P.h1s0L : nullptr,
                   last ? P.cb1 : nullptr);
      }
      gsync(P.flags, ++ep * NB_);
    }
  }
}

// ============================ decoder (cooperative persistent) ============================

struct DP {
  const float* out_emb; const int* target; const int* tfm;
  const _Float16 *dWH, *dWL;
  const float *decbih, *decbhh;
  const _Float16 *WoH, *WoL;
  const float* bout;
  _Float16 *hd0H, *hd0L;            // 2 parity slots (layer0 h)
  _Float16 *histH, *histL;          // 64 slots; slot i+1 = h1 of step i
  const float *cb0, *cb1;
  unsigned long long* amax;
  unsigned* flags;
};

template <int XM>
__device__ void dcell(const _Float16* __restrict__ WH, const _Float16* __restrict__ WL,
                      const float* __restrict__ bih, const float* __restrict__ bhh,
                      const _Float16* __restrict__ xH, const _Float16* __restrict__ xL,
                      const float* __restrict__ out_emb, const int* __restrict__ target,
                      const int* __restrict__ tfm, const unsigned long long* __restrict__ amax,
                      const _Float16* __restrict__ hH, const _Float16* __restrict__ hL,
                      _Float16* __restrict__ oH, _Float16* __restrict__ oL,
                      float& c, int step, float* sScr, int blk, int tid) {
  int w = tid >> 6, lane = tid & 63;
  int j16 = lane & 15;
  int g_ = j16 >> 2, u_ = j16 & 3;
  int grow = g_ * 1024 + blk * 4 + u_;
  int kbase = w * 256;
  bool xp = (w < 4);

  int tok0 = 0, tok1 = 0;
  if (XM == 2 && xp) {
    int b0 = lane & 15, b1 = 16 + (lane & 15);
    if (step == 0)          { tok0 = target[b0 * Tt_];        tok1 = target[b1 * Tt_]; }
    else if (tfm[step] > 0) { tok0 = target[b0 * Tt_ + step]; tok1 = target[b1 * Tt_ + step]; }
    else { tok0 = (int)(~(unsigned)amax[b0]); tok1 = (int)(~(unsigned)amax[b1]); }
  }
  const _Float16* aH = xp ? xH : (hH - 1024);
  const _Float16* aL = xp ? xL : (hL - 1024);

  f4 accH[2] = {}, accM[2] = {};
  for (int ks = 0; ks < 8; ++ks) {
    int kk = kbase + ks * 32 + (lane >> 4) * 8;
    h8 Bh = *(const h8*)(WH + (size_t)grow * 2048 + kk);
    h8 Bl = *(const h8*)(WL + (size_t)grow * 2048 + kk);
#pragma unroll
    for (int mt = 0; mt < 2; ++mt) {
      int brow = mt * 16 + (lane & 15);
      h8 Ah, Al;
      if (XM == 2 && xp) {
        int tk = mt ? tok1 : tok0;
        split8p(out_emb + (size_t)tk * 1024 + kk, Ah, Al);
      } else {
        Ah = *(const h8*)(aH + (size_t)brow * 1024 + kk);
        Al = *(const h8*)(aL + (size_t)brow * 1024 + kk);
      }
      accH[mt] = MFMA16(Ah, Bh, accH[mt]);
      accM[mt] = MFMA16(Ah, Bl, accM[mt]);
      accM[mt] = MFMA16(Al, Bh, accM[mt]);
    }
  }
#pragma unroll
  for (int mt = 0; mt < 2; ++mt)
#pragma unroll
    for (int r = 0; r < 4; ++r) {
      int b = mt * 16 + (lane >> 4) * 4 + r;
      sScr[w * 544 + b * 17 + j16] = accH[mt][r] + accM[mt][r] * (1.0f / 2048.0f);
    }
  __syncthreads();
  if (tid < 128) {
    int u = tid >> 5, b = tid & 31;
    float g[4];
#pragma unroll
    for (int gg = 0; gg < 4; ++gg) {
      int j = gg * 4 + u;
      float s = 0.0f;
#pragma unroll
      for (int ww = 0; ww < 8; ++ww) s += sScr[ww * 544 + b * 17 + j];
      int growf = gg * 1024 + blk * 4 + u;
      g[gg] = s + bih[growf] + bhh[growf];
    }
    float ii = 1.0f / (1.0f + expf(-g[0]));
    float ff = 1.0f / (1.0f + expf(-g[1]));
    float gt = tanhf(g[2]);
    float oo = 1.0f / (1.0f + expf(-g[3]));
    c = ff * c + ii * gt;
    float hn = oo * tanhf(c);
    _Float16 hh = (_Float16)hn;
    int col = blk * 4 + u;
    size_t ci = (size_t)b * 1024 + col;
    oH[ci] = hh;
    oL[ci] = (_Float16)((hn - (float)hh) * 2048.0f);
  }
}

__global__ void __launch_bounds__(512, 4) voice_dec(DP P) {
  __shared__ float sScr[8 * 544];
  int blk = blockIdx.x, tid = threadIdx.x;
  unsigned ep = 0;
  float c0 = 0.0f, c1 = 0.0f;
  if (tid < 128) {
    int u = tid >> 5, b = tid & 31;
    size_t ci = (size_t)b * 1024 + blk * 4 + u;
    c0 = P.cb0[ci];
    c1 = P.cb1[ci];
  }

  for (int i = 0; i < 63; ++i) {
    int p = i & 1;
    _Float16* h0in   = P.hd0H + (size_t)p * 32768;        _Float16* h0inL  = P.hd0L + (size_t)p * 32768;
    _Float16* h0out  = P.hd0H + (size_t)(p ^ 1) * 32768;  _Float16* h0outL = P.hd0L + (size_t)(p ^ 1) * 32768;
    _Float16* h1in   = P.histH + (size_t)i * 32768;       _Float16* h1inL  = P.histL + (size_t)i * 32768;
    _Float16* h1out  = P.histH + (size_t)(i + 1) * 32768; _Float16* h1outL = P.histL + (size_t)(i + 1) * 32768;

    dcell<2>(P.dWH, P.dWL, P.decbih, P.decbhh,
             nullptr, nullptr, P.out_emb, P.target, P.tfm, P.amax,
             h0in, h0inL, h0out, h0outL, c0, i, sScr, blk, tid);
    gsync(P.flags, ++ep * NB_);

    if (blk == 0 && tid < 32) P.amax[tid] = 0ull;
    dcell<0>(P.dWH + (size_t)4096 * 2048, P.dWL + (size_t)4096 * 2048,
             P.decbih + 4096, P.decbhh + 4096,
             h0out, h0outL, nullptr, nullptr, nullptr, nullptr,
             h1in, h1inL, h1out, h1outL, c1, i, sScr, blk, tid);
    gsync(P.flags, ++ep * NB_);

    // argmax-only projection, only when step i+1 consumes it
    bool needC = (i < 62) && (P.tfm[i + 1] == 0);
    if (needC) {
      int w = tid >> 6, lane = tid & 63;
      int vt = blk * 8 + w;
      if (vt < 2000) {
        int vcol = vt * 16 + (lane & 15);
        int kof = (lane >> 4) * 8;
        f4 accH[2] = {}, accM[2] = {};
        for (int ks = 0; ks < 32; ++ks) {
          int kk = ks * 32 + kof;
          h8 Bh = *(const h8*)(P.WoH + (size_t)vcol * 1024 + kk);
          h8 Bl = *(const h8*)(P.WoL + (size_t)vcol * 1024 + kk);
#pragma unroll
          for (int mt = 0; mt < 2; ++mt) {
            int brow = mt * 16 + (lane & 15);
            h8 Ah = *(const h8*)(h1out  + (size_t)brow * 1024 + kk);
            h8 Al = *(const h8*)(h1outL + (size_t)brow * 1024 + kk);
            accH[mt] = MFMA16(Ah, Bh, accH[mt]);
            accM[mt] = MFMA16(Ah, Bl, accM[mt]);
            accM[mt] = MFMA16(Al, Bh, accM[mt]);
          }
        }
        float bias = P.bout[vcol];
#pragma unroll
        for (int mt = 0; mt < 2; ++mt) {
          float vr[4];
#pragma unroll
          for (int r = 0; r < 4; ++r)
            vr[r] = accH[mt][r] + accM[mt][r] * (1.0f / 2048.0f) + bias;
#pragma unroll
          for (int r = 0; r < 4; ++r) {
            float v = vr[r];
            unsigned id = (unsigned)vcol;
#pragma unroll
            for (int off = 1; off < 16; off <<= 1) {
              float ov = __shfl_xor(v, off, 64);
              unsigned oi = __shfl_xor(id, off, 64);
              if (ov > v || (ov == v && oi < id)) { v = ov; id = oi; }
            }
            if ((lane & 15) == 0) {
              unsigned kb = __float_as_uint(v);
              kb = (kb & 0x80000000u) ? ~kb : (kb | 0x80000000u);
              unsigned long long key = ((unsigned long long)kb << 32) | (unsigned)(~id);
              int b = mt * 16 + (lane >> 4) * 4 + r;
              if (P.amax[b] < key) atomicMax(&P.amax[b], key);
            }
          }
        }
      }
      gsync(P.flags, ++ep * NB_);
    }
  }
}

// ============================ final batched output GEMM ============================
__global__ void __launch_bounds__(256, 2)
k_out(const _Float16* __restrict__ histH, const _Float16* __restrict__ histL,
      const _Float16* __restrict__ WoH, const _Float16* __restrict__ WoL,
      const float* __restrict__ bout, float* __restrict__ out) {
  int bid = blockIdx.x;          // 8000 = 500 nb x 16 mg
  int nb = bid / 16, mg = bid % 16;
  int w = threadIdx.x >> 6, lane = threadIdx.x & 63;
  int kof = (lane >> 4) * 8;
  int mt0 = mg * 8 + w * 2;
  f4 accH[2][4] = {}, accM[2][4] = {};
  for (int ks = 0; ks < 32; ++ks) {
    int kk = ks * 32 + kof;
    h8 Ah[2], Al[2];
#pragma unroll
    for (int mti = 0; mti < 2; ++mti) {
      int mt = mt0 + mti;
      if (mt < 126) {
        int m = mt * 16 + (lane & 15);
        int ii = m >> 5, b = m & 31;
        size_t ai = (size_t)(ii + 1) * 32768 + (size_t)b * 1024 + kk;
        Ah[mti] = *(const h8*)(histH + ai);
        Al[mti] = *(const h8*)(histL + ai);
      }
    }
#pragma unroll
    for (int nt = 0; nt < 4; ++nt) {
      int vcol = (nb * 4 + nt) * 16 + (lane & 15);
      h8 Bh = *(const h8*)(WoH + (size_t)vcol * 1024 + kk);
      h8 Bl = *(const h8*)(WoL + (size_t)vcol * 1024 + kk);
#pragma unroll
      for (int mti = 0; mti < 2; ++mti) {
        if (mt0 + mti < 126) {
          accH[mti][nt] = MFMA16(Ah[mti], Bh, accH[mti][nt]);
          accM[mti][nt] = MFMA16(Ah[mti], Bl, accM[mti][nt]);
          accM[mti][nt] = MFMA16(Al[mti], Bh, accM[mti][nt]);
        }
      }
    }
  }
#pragma unroll
  for (int mti = 0; mti < 2; ++mti) {
    int mt = mt0 + mti;
    if (mt >= 126) continue;
#pragma unroll
    for (int nt = 0; nt < 4; ++nt) {
      int vcol = (nb * 4 + nt) * 16 + (lane & 15);
      float bias = bout[vcol];
#pragma unroll
      for (int r = 0; r < 4; ++r) {
        int m = mt * 16 + (lane >> 4) * 4 + r;
        int ii = m >> 5, b = m & 31;
        out[(size_t)b * (Tt_ * V_) + (size_t)(ii + 1) * V_ + vcol] =
            accH[mti][nt][r] + accM[mti][nt][r] * (1.0f / 2048.0f) + bias;
      }
    }
  }
}

// ============================ host ============================

extern "C" void kernel_launch(void* const* d_in, const int* in_sizes, int n_in,
                              void* d_out, int out_size, void* d_ws, size_t ws_size,
                              hipStream_t stream) {
  const int*   itoks   = (const int*)d_in[0];
  const int*   target  = (const int*)d_in[1];
  const int*   tfm     = (const int*)d_in[2];
  const float* in_emb  = (const float*)d_in[3];
  const float* out_emb = (const float*)d_in[4];
  const float* encWih  = (const float*)d_in[5];
  const float* encWhh  = (const float*)d_in[6];
  const float* encbih  = (const float*)d_in[7];
  const float* encbhh  = (const float*)d_in[8];
  const float* decWih  = (const float*)d_in[9];
  const float* decWhh  = (const float*)d_in[10];
  const float* decbih  = (const float*)d_in[11];
  const float* decbhh  = (const float*)d_in[12];
  const float* Wout    = (const float*)d_in[13];
  const float* bout    = (const float*)d_in[14];
  float* out = (float*)d_out;

  char* ws = (char*)d_ws;
  size_t off = 0;
  auto alloc = [&](size_t bytes) { void* p = ws + off; off += (bytes + 255) & ~(size_t)255; return p; };
  _Float16* seqH = (_Float16*)alloc((size_t)129 * 32768 * 2);
  _Float16* seqL = (_Float16*)alloc((size_t)129 * 32768 * 2);
  _Float16* embH = (_Float16*)alloc((size_t)128 * 32768 * 2);
  _Float16* embL = (_Float16*)alloc((size_t)128 * 32768 * 2);
  _Float16* he1H = (_Float16*)alloc((size_t)2 * 32768 * 2);
  _Float16* he1L = (_Float16*)alloc((size_t)2 * 32768 * 2);
  _Float16* hd0H = (_Float16*)alloc((size_t)2 * 32768 * 2);
  _Float16* hd0L = (_Float16*)alloc((size_t)2 * 32768 * 2);
  _Float16* histH = (_Float16*)alloc((size_t)64 * 32768 * 2);
  _Float16* histL = (_Float16*)alloc((size_t)64 * 32768 * 2);
  float*    cb0  = (float*)alloc((size_t)32 * 1024 * 4);
  float*    cb1  = (float*)alloc((size_t)32 * 1024 * 4);
  _Float16* dWH  = (_Float16*)alloc((size_t)2 * 4096 * 2048 * 2);
  _Float16* dWL  = (_Float16*)alloc((size_t)2 * 4096 * 2048 * 2);
  _Float16* WoH  = (_Float16*)alloc((size_t)32000 * 1024 * 2);
  _Float16* WoL  = (_Float16*)alloc((size_t)32000 * 1024 * 2);
  unsigned long long* amax = (unsigned long long*)alloc(32 * 8);
  unsigned* encF = (unsigned*)alloc(NB_ * 4 * 4);
  unsigned* decF = (unsigned*)alloc(NB_ * 4 * 4);
  if (off > ws_size) return;

  k_init<<<1, 256, 0, stream>>>(encF, decF);
  k_split_dec<<<2 * 4096, 256, 0, stream>>>(decWih, decWhh, dWH, dWL);
  k_split_wout<<<32000, 128, 0, stream>>>(Wout, WoH, WoL);
  k_emb<<<4096, 128, 0, stream>>>(itoks, in_emb, embH, embL);

  EP E;
  E.encWih = encWih; E.encWhh = encWhh; E.encbih = encbih; E.encbhh = encbhh;
  E.out = out; E.embH = embH; E.embL = embL;
  E.seqH = seqH; E.seqL = seqL; E.he1H = he1H; E.he1L = he1L;
  E.hd0H = hd0H; E.hd0L = hd0L; E.h1s0H = histH; E.h1s0L = histL;
  E.cb0 = cb0; E.cb1 = cb1; E.flags = encF;
  void* eargs[] = { &E };
  hipLaunchCooperativeKernel((void*)voice_enc, dim3(NB_), dim3(256), eargs, 0, stream);

  DP D;
  D.out_emb = out_emb; D.target = target; D.tfm = tfm;
  D.dWH = dWH; D.dWL = dWL; D.decbih = decbih; D.decbhh = decbhh;
  D.WoH = WoH; D.WoL = WoL; D.bout = bout;
  D.hd0H = hd0H; D.hd0L = hd0L; D.histH = histH; D.histL = histL;
  D.cb0 = cb0; D.cb1 = cb1; D.amax = amax; D.flags = decF;
  void* dargs[] = { &D };
  hipLaunchCooperativeKernel((void*)voice_dec, dim3(NB_), dim3(512), dargs, 0, stream);

  k_out<<<8000, 256, 0, stream>>>(histH, histL, WoH, WoL, bout, out);
}

// Round 6
// 11392.265 us; speedup vs baseline: 2.6785x; 1.2082x over previous
//
#include <hip/hip_runtime.h>
#include <cstdint>

#define S_  128
#define Tt_ 64
#define V_  32000
#define NB_ 256

typedef _Float16 h8 __attribute__((ext_vector_type(8)));
typedef float    f4 __attribute__((ext_vector_type(4)));

#define MFMA16(a,b,c) __builtin_amdgcn_mfma_f32_16x16x32_f16((a),(b),(c),0,0,0)

__device__ __forceinline__ void split8p(const float* __restrict__ p, h8& hi, h8& lo) {
  f4 a = *(const f4*)p;
  f4 b = *(const f4*)(p + 4);
#pragma unroll
  for (int i = 0; i < 4; i++) {
    _Float16 h0 = (_Float16)a[i];
    hi[i] = h0; lo[i] = (_Float16)((a[i] - (float)h0) * 2048.0f);
    _Float16 h1 = (_Float16)b[i];
    hi[i+4] = h1; lo[i+4] = (_Float16)((b[i] - (float)h1) * 2048.0f);
  }
}

// ---- fence-free device barrier ----
// Protocol: all cross-block data is either (a) written via agent-scope atomic
// stores (write-through to LLC) to virgin addresses and read with plain cached
// loads (no stale copy can exist), or (b) amax/flags accessed via atomics.
// So no wbL2/invL2 fences are needed; barrier = vmcnt drain + flag handshake.
__device__ __forceinline__ void gsync(unsigned* flags, unsigned target) {
  asm volatile("s_waitcnt vmcnt(0)" ::: "memory");   // all atomic stores at LLC
  __syncthreads();
  int tid = threadIdx.x;
  if (tid == 0) {
    __hip_atomic_store(&flags[blockIdx.x * 4], target, __ATOMIC_RELAXED,
                       __HIP_MEMORY_SCOPE_AGENT);
  }
  if (tid < 64) {
    bool done;
    do {
      unsigned m = 0xFFFFFFFFu;
#pragma unroll
      for (int q = 0; q < 4; ++q) {
        unsigned f = __hip_atomic_load(&flags[(tid + q * 64) * 4], __ATOMIC_RELAXED,
                                       __HIP_MEMORY_SCOPE_AGENT);
        m = m < f ? m : f;
      }
      done = (bool)__all(m >= target);
      if (!done) __builtin_amdgcn_s_sleep(1);
    } while (!done);
  }
  __builtin_amdgcn_sched_barrier(0);
  __syncthreads();
  asm volatile("" ::: "memory");
}

// write hi/lo fp16 h-state as packed u32 agent-scope atomic stores.
// caller: tid<128, lane=tid&63, u=tid>>5, b=tid&31, col0=blk*4+(u&2).
__device__ __forceinline__ void store_h_pair(_Float16* __restrict__ oH,
                                             _Float16* __restrict__ oL,
                                             int b, int col0, int lane,
                                             _Float16 hh, _Float16 hl) {
  unsigned hs = (unsigned)__builtin_bit_cast(unsigned short, hh);
  unsigned ls = (unsigned)__builtin_bit_cast(unsigned short, hl);
  unsigned ph = (unsigned)__shfl_xor((int)hs, 32, 64);
  unsigned pl = (unsigned)__shfl_xor((int)ls, 32, 64);
  if (lane < 32) {
    unsigned hw = hs | (ph << 16);
    __hip_atomic_store((unsigned*)(oH + (size_t)b * 1024 + col0), hw,
                       __ATOMIC_RELAXED, __HIP_MEMORY_SCOPE_AGENT);
  } else {
    unsigned lw = pl | (ls << 16);
    __hip_atomic_store((unsigned*)(oL + (size_t)b * 1024 + col0), lw,
                       __ATOMIC_RELAXED, __HIP_MEMORY_SCOPE_AGENT);
  }
}

// ============================ prep kernels ============================

// zero: out[:,0,:], seq slot0, ehist slot0, flag arrays (all cross-kernel)
__global__ void k_prep0(float* __restrict__ out,
                        _Float16* __restrict__ seqH, _Float16* __restrict__ seqL,
                        _Float16* __restrict__ ehH, _Float16* __restrict__ ehL,
                        unsigned* __restrict__ encF, unsigned* __restrict__ decF) {
  int stride = gridDim.x * 256;
  for (unsigned idx = blockIdx.x * 256 + threadIdx.x; idx < 32u * V_; idx += stride) {
    unsigned b = idx / V_, v = idx - b * V_;
    out[(size_t)b * (Tt_ * V_) + v] = 0.0f;
  }
  for (unsigned idx = blockIdx.x * 256 + threadIdx.x; idx < 16384; idx += stride) {
    ((unsigned*)seqH)[idx] = 0u; ((unsigned*)seqL)[idx] = 0u;
    ((unsigned*)ehH)[idx]  = 0u; ((unsigned*)ehL)[idx]  = 0u;
  }
  for (unsigned idx = blockIdx.x * 256 + threadIdx.x; idx < NB_ * 4; idx += stride) {
    encF[idx] = 0u; decF[idx] = 0u;
  }
}

__global__ void k_split_dec(const float* __restrict__ decWih, const float* __restrict__ decWhh,
                            _Float16* __restrict__ WH, _Float16* __restrict__ WL) {
  int blk = blockIdx.x;               // 2*4096
  int tid = threadIdx.x;              // 256
  int l = blk >> 12, grow = blk & 4095;
  int k = tid * 8;
  const float* src = (k < 1024) ? (decWih + ((size_t)l * 4096 + grow) * 1024 + k)
                                : (decWhh + ((size_t)l * 4096 + grow) * 1024 + (k - 1024));
  h8 hi, lo;
  split8p(src, hi, lo);
  size_t d = ((size_t)l * 4096 + grow) * 2048 + k;
  *(h8*)(WH + d) = hi;
  *(h8*)(WL + d) = lo;
}

__global__ void k_split_wout(const float* __restrict__ Wout,
                             _Float16* __restrict__ WoH, _Float16* __restrict__ WoL) {
  int row = blockIdx.x;               // 32000
  int k = threadIdx.x * 8;            // 128 thr
  h8 hi, lo;
  split8p(Wout + (size_t)row * 1024 + k, hi, lo);
  *(h8*)(WoH + (size_t)row * 1024 + k) = hi;
  *(h8*)(WoL + (size_t)row * 1024 + k) = lo;
}

__global__ void k_emb(const int* __restrict__ itoks, const float* __restrict__ in_emb,
                      _Float16* __restrict__ embH, _Float16* __restrict__ embL) {
  int n = blockIdx.x;                 // 4096
  int b = n & 31, t = n >> 5;
  int tok = itoks[b * S_ + t];
  int k = threadIdx.x * 8;            // 128 thr
  h8 hi, lo;
  split8p(in_emb + (size_t)tok * 1024 + k, hi, lo);
  *(h8*)(embH + (size_t)n * 1024 + k) = hi;
  *(h8*)(embL + (size_t)n * 1024 + k) = lo;
}

// ============================ encoder (cooperative) ============================

struct EP {
  const float* encWih; const float* encWhh; const float* encbih; const float* encbhh;
  const _Float16 *embH, *embL;
  _Float16 *seqH, *seqL;    // 129 slots (layer0 h history; slot t+1 = h at step t)
  _Float16 *ehH, *ehL;      // 129 slots (layer1 h history)
  _Float16 *h0s0H, *h0s0L;  // hist0 slot 0 (final enc layer0 h) - cross-kernel
  _Float16 *h1s0H, *h1s0L;  // hist1 slot 0 (final enc layer1 h) - cross-kernel
  float *cb0, *cb1;
  unsigned* flags;
};

__device__ __forceinline__ int wadr(int row, int k) {
  return row * 2048 + ((((k << 1) ^ ((row & 7) << 4))) >> 1);
}

__device__ void preload_enc(const float* __restrict__ Wih, const float* __restrict__ Whh,
                            int blk, int tid, _Float16* sWH, _Float16* sWL) {
#pragma unroll 4
  for (int it = 0; it < 32; ++it) {
    int lin = (it * 256 + tid) * 4;
    int j16 = lin >> 11;
    int k   = lin & 2047;
    int g = j16 >> 2, u = j16 & 3;
    int grow = g * 1024 + blk * 4 + u;
    const float* src = (k < 1024) ? (Wih + (size_t)grow * 1024 + k)
                                  : (Whh + (size_t)grow * 1024 + (k - 1024));
    f4 x = *(const f4*)src;
#pragma unroll
    for (int q = 0; q < 4; q++) {
      _Float16 hh = (_Float16)x[q];
      sWH[wadr(j16, k + q)] = hh;
      sWL[wadr(j16, k + q)] = (_Float16)((x[q] - (float)hh) * 2048.0f);
    }
  }
}

__device__ void gates_enc(const _Float16* sWH, const _Float16* sWL, float* sScr,
                          const _Float16* __restrict__ xH, const _Float16* __restrict__ xL,
                          const _Float16* __restrict__ hHb, const _Float16* __restrict__ hLb,
                          int tid) {
  int w = tid >> 6, lane = tid & 63;
  int kbase = w * 512;
  bool xp = (w < 2);
  int j16 = lane & 15;
  const _Float16* aH = xp ? xH : (hHb - 1024);
  const _Float16* aL = xp ? xL : (hLb - 1024);
  f4 accH[2] = {}, accM[2] = {};
  for (int ks = 0; ks < 16; ++ks) {
    int kk = kbase + ks * 32 + (lane >> 4) * 8;
    h8 Bh = *(const h8*)(sWH + wadr(j16, kk));
    h8 Bl = *(const h8*)(sWL + wadr(j16, kk));
#pragma unroll
    for (int mt = 0; mt < 2; ++mt) {
      int brow = mt * 16 + (lane & 15);
      h8 Ah = *(const h8*)(aH + (size_t)brow * 1024 + kk);
      h8 Al = *(const h8*)(aL + (size_t)brow * 1024 + kk);
      accH[mt] = MFMA16(Ah, Bh, accH[mt]);
      accM[mt] = MFMA16(Ah, Bl, accM[mt]);
      accM[mt] = MFMA16(Al, Bh, accM[mt]);
    }
  }
#pragma unroll
  for (int mt = 0; mt < 2; ++mt)
#pragma unroll
    for (int r = 0; r < 4; ++r) {
      int b = mt * 16 + (lane >> 4) * 4 + r;
      sScr[w * 544 + b * 17 + j16] = accH[mt][r] + accM[mt][r] * (1.0f / 2048.0f);
    }
}

__device__ void finish_enc(float* sScr, int blk, int tid,
                           const float* __restrict__ bih, const float* __restrict__ bhh,
                           float& c,
                           _Float16* __restrict__ oH, _Float16* __restrict__ oL,
                           _Float16* __restrict__ oH2, _Float16* __restrict__ oL2,
                           float* __restrict__ cOut) {
  __syncthreads();
  if (tid < 128) {
    int u = tid >> 5, b = tid & 31, lane = tid & 63;
    float g[4];
#pragma unroll
    for (int gg = 0; gg < 4; ++gg) {
      int j = gg * 4 + u;
      float s = sScr[0 * 544 + b * 17 + j] + sScr[1 * 544 + b * 17 + j]
              + sScr[2 * 544 + b * 17 + j] + sScr[3 * 544 + b * 17 + j];
      int grow = gg * 1024 + blk * 4 + u;
      g[gg] = s + bih[grow] + bhh[grow];
    }
    float ii = 1.0f / (1.0f + expf(-g[0]));
    float ff = 1.0f / (1.0f + expf(-g[1]));
    float gt = tanhf(g[2]);
    float oo = 1.0f / (1.0f + expf(-g[3]));
    c = ff * c + ii * gt;
    float hn = oo * tanhf(c);
    _Float16 hh = (_Float16)hn;
    _Float16 hl = (_Float16)((hn - (float)hh) * 2048.0f);
    int col0 = blk * 4 + (u & 2);
    store_h_pair(oH, oL, b, col0, lane, hh, hl);   // agent write-through
    size_t ci = (size_t)b * 1024 + blk * 4 + u;
    if (oH2) { oH2[ci] = hh; oL2[ci] = hl; }       // cross-kernel: normal stores
    if (cOut) cOut[ci] = c;
  }
}

__global__ void __launch_bounds__(256, 1) voice_enc(EP P) {
  __shared__ _Float16 sWH[16 * 2048];
  __shared__ _Float16 sWL[16 * 2048];
  __shared__ float    sScr[4 * 544];
  int blk = blockIdx.x, tid = threadIdx.x;
  float cA = 0.0f, cB = 0.0f;
  unsigned ep = 0;

  for (int l = 0; l < 2; ++l) {
    const float* Wih = P.encWih + (size_t)l * 4096 * 1024;
    const float* Whh = P.encWhh + (size_t)l * 4096 * 1024;
    const float* bih = P.encbih + (size_t)l * 4096;
    const float* bhh = P.encbhh + (size_t)l * 4096;
    preload_enc(Wih, Whh, blk, tid, sWH, sWL);
    __syncthreads();
    for (int t = 0; t < 128; ++t) {
      bool last = (t == 127);
      if (l == 0) {
        gates_enc(sWH, sWL, sScr,
                  P.embH + (size_t)t * 32768, P.embL + (size_t)t * 32768,
                  P.seqH + (size_t)t * 32768, P.seqL + (size_t)t * 32768, tid);
        finish_enc(sScr, blk, tid, bih, bhh, cA,
                   P.seqH + (size_t)(t + 1) * 32768, P.seqL + (size_t)(t + 1) * 32768,
                   last ? P.h0s0H : nullptr, last ? P.h0s0L : nullptr,
                   last ? P.cb0 : nullptr);
      } else {
        gates_enc(sWH, sWL, sScr,
                  P.seqH + (size_t)(t + 1) * 32768, P.seqL + (size_t)(t + 1) * 32768,
                  P.ehH + (size_t)t * 32768, P.ehL + (size_t)t * 32768, tid);
        finish_enc(sScr, blk, tid, bih, bhh, cB,
                   P.ehH + (size_t)(t + 1) * 32768, P.ehL + (size_t)(t + 1) * 32768,
                   last ? P.h1s0H : nullptr, last ? P.h1s0L : nullptr,
                   last ? P.cb1 : nullptr);
      }
      gsync(P.flags, ++ep * NB_);
    }
  }
}

// ============================ decoder (cooperative persistent) ============================

struct DP {
  const float* out_emb; const int* target; const int* tfm;
  const _Float16 *dWH, *dWL;
  const float *decbih, *decbhh;
  const _Float16 *WoH, *WoL;
  const float* bout;
  _Float16 *hist0H, *hist0L;        // 64 slots; slot i+1 = layer0 h of step i
  _Float16 *hist1H, *hist1L;        // 64 slots; slot i+1 = layer1 h of step i
  const float *cb0, *cb1;
  unsigned long long* amax;
  unsigned* flags;
};

template <int XM>
__device__ void dcell(const _Float16* __restrict__ WH, const _Float16* __restrict__ WL,
                      const float* __restrict__ bih, const float* __restrict__ bhh,
                      const _Float16* __restrict__ xH, const _Float16* __restrict__ xL,
                      const float* __restrict__ out_emb, const int* __restrict__ target,
                      const int* __restrict__ tfm, unsigned long long* __restrict__ amax,
                      const _Float16* __restrict__ hH, const _Float16* __restrict__ hL,
                      _Float16* __restrict__ oH, _Float16* __restrict__ oL,
                      float& c, int step, float* sScr, int blk, int tid) {
  int w = tid >> 6, lane = tid & 63;
  int j16 = lane & 15;
  int g_ = j16 >> 2, u_ = j16 & 3;
  int grow = g_ * 1024 + blk * 4 + u_;
  int kbase = w * 256;
  bool xp = (w < 4);

  int tok0 = 0, tok1 = 0;
  if (XM == 2 && xp) {
    int b0 = lane & 15, b1 = 16 + (lane & 15);
    if (step == 0)          { tok0 = target[b0 * Tt_];        tok1 = target[b1 * Tt_]; }
    else if (tfm[step] > 0) { tok0 = target[b0 * Tt_ + step]; tok1 = target[b1 * Tt_ + step]; }
    else {
      unsigned long long a0 = __hip_atomic_load(&amax[b0], __ATOMIC_RELAXED, __HIP_MEMORY_SCOPE_AGENT);
      unsigned long long a1 = __hip_atomic_load(&amax[b1], __ATOMIC_RELAXED, __HIP_MEMORY_SCOPE_AGENT);
      tok0 = (int)(~(unsigned)a0); tok1 = (int)(~(unsigned)a1);
    }
  }
  const _Float16* aH = xp ? xH : (hH - 1024);
  const _Float16* aL = xp ? xL : (hL - 1024);

  // preload all weight fragments (16 b128 loads in flight -> HBM stream)
  h8 Bh[8], Bl[8];
#pragma unroll
  for (int ks = 0; ks < 8; ++ks) {
    int kk = kbase + ks * 32 + (lane >> 4) * 8;
    Bh[ks] = *(const h8*)(WH + (size_t)grow * 2048 + kk);
    Bl[ks] = *(const h8*)(WL + (size_t)grow * 2048 + kk);
  }
  f4 accH[2] = {}, accM[2] = {};
#pragma unroll
  for (int ks = 0; ks < 8; ++ks) {
    int kk = kbase + ks * 32 + (lane >> 4) * 8;
#pragma unroll
    for (int mt = 0; mt < 2; ++mt) {
      int brow = mt * 16 + (lane & 15);
      h8 Ah, Al;
      if (XM == 2 && xp) {
        int tk = mt ? tok1 : tok0;
        split8p(out_emb + (size_t)tk * 1024 + kk, Ah, Al);
      } else {
        Ah = *(const h8*)(aH + (size_t)brow * 1024 + kk);
        Al = *(const h8*)(aL + (size_t)brow * 1024 + kk);
      }
      accH[mt] = MFMA16(Ah, Bh[ks], accH[mt]);
      accM[mt] = MFMA16(Ah, Bl[ks], accM[mt]);
      accM[mt] = MFMA16(Al, Bh[ks], accM[mt]);
    }
  }
#pragma unroll
  for (int mt = 0; mt < 2; ++mt)
#pragma unroll
    for (int r = 0; r < 4; ++r) {
      int b = mt * 16 + (lane >> 4) * 4 + r;
      sScr[w * 544 + b * 17 + j16] = accH[mt][r] + accM[mt][r] * (1.0f / 2048.0f);
    }
  __syncthreads();
  if (tid < 128) {
    int u = tid >> 5, b = tid & 31, lanef = tid & 63;
    float g[4];
#pragma unroll
    for (int gg = 0; gg < 4; ++gg) {
      int j = gg * 4 + u;
      float s = 0.0f;
#pragma unroll
      for (int ww = 0; ww < 8; ++ww) s += sScr[ww * 544 + b * 17 + j];
      int growf = gg * 1024 + blk * 4 + u;
      g[gg] = s + bih[growf] + bhh[growf];
    }
    float ii = 1.0f / (1.0f + expf(-g[0]));
    float ff = 1.0f / (1.0f + expf(-g[1]));
    float gt = tanhf(g[2]);
    float oo = 1.0f / (1.0f + expf(-g[3]));
    c = ff * c + ii * gt;
    float hn = oo * tanhf(c);
    _Float16 hh = (_Float16)hn;
    _Float16 hl = (_Float16)((hn - (float)hh) * 2048.0f);
    int col0 = blk * 4 + (u & 2);
    store_h_pair(oH, oL, b, col0, lanef, hh, hl);
  }
}

__global__ void __launch_bounds__(512, 2) voice_dec(DP P) {
  __shared__ float sScr[8 * 544];
  int blk = blockIdx.x, tid = threadIdx.x;
  unsigned ep = 0;
  float c0 = 0.0f, c1 = 0.0f;
  if (tid < 128) {
    int u = tid >> 5, b = tid & 31;
    size_t ci = (size_t)b * 1024 + blk * 4 + u;
    c0 = P.cb0[ci];
    c1 = P.cb1[ci];
  }

  for (int i = 0; i < 63; ++i) {
    _Float16* h0in   = P.hist0H + (size_t)i * 32768;       _Float16* h0inL  = P.hist0L + (size_t)i * 32768;
    _Float16* h0out  = P.hist0H + (size_t)(i + 1) * 32768; _Float16* h0outL = P.hist0L + (size_t)(i + 1) * 32768;
    _Float16* h1in   = P.hist1H + (size_t)i * 32768;       _Float16* h1inL  = P.hist1L + (size_t)i * 32768;
    _Float16* h1out  = P.hist1H + (size_t)(i + 1) * 32768; _Float16* h1outL = P.hist1L + (size_t)(i + 1) * 32768;

    dcell<2>(P.dWH, P.dWL, P.decbih, P.decbhh,
             nullptr, nullptr, P.out_emb, P.target, P.tfm, P.amax,
             h0in, h0inL, h0out, h0outL, c0, i, sScr, blk, tid);
    gsync(P.flags, ++ep * NB_);

    if (blk == 0 && tid < 32)
      __hip_atomic_store(&P.amax[tid], 0ull, __ATOMIC_RELAXED, __HIP_MEMORY_SCOPE_AGENT);
    dcell<0>(P.dWH + (size_t)4096 * 2048, P.dWL + (size_t)4096 * 2048,
             P.decbih + 4096, P.decbhh + 4096,
             h0out, h0outL, nullptr, nullptr, nullptr, P.amax,
             h1in, h1inL, h1out, h1outL, c1, i, sScr, blk, tid);
    gsync(P.flags, ++ep * NB_);

    // argmax-only projection, only when step i+1 consumes it
    bool needC = (i < 62) && (P.tfm[i + 1] == 0);
    if (needC) {
      int w = tid >> 6, lane = tid & 63;
      int vt = blk * 8 + w;
      if (vt < 2000) {
        int vcol = vt * 16 + (lane & 15);
        int kof = (lane >> 4) * 8;
        f4 accH[2] = {}, accM[2] = {};
#pragma unroll 4
        for (int ks = 0; ks < 32; ++ks) {
          int kk = ks * 32 + kof;
          h8 Bh = __builtin_nontemporal_load((const h8*)(P.WoH + (size_t)vcol * 1024 + kk));
          h8 Bl = __builtin_nontemporal_load((const h8*)(P.WoL + (size_t)vcol * 1024 + kk));
#pragma unroll
          for (int mt = 0; mt < 2; ++mt) {
            int brow = mt * 16 + (lane & 15);
            h8 Ah = *(const h8*)(h1out  + (size_t)brow * 1024 + kk);
            h8 Al = *(const h8*)(h1outL + (size_t)brow * 1024 + kk);
            accH[mt] = MFMA16(Ah, Bh, accH[mt]);
            accM[mt] = MFMA16(Ah, Bl, accM[mt]);
            accM[mt] = MFMA16(Al, Bh, accM[mt]);
          }
        }
        float bias = P.bout[vcol];
#pragma unroll
        for (int mt = 0; mt < 2; ++mt) {
          float vr[4];
#pragma unroll
          for (int r = 0; r < 4; ++r)
            vr[r] = accH[mt][r] + accM[mt][r] * (1.0f / 2048.0f) + bias;
#pragma unroll
          for (int r = 0; r < 4; ++r) {
            float v = vr[r];
            unsigned id = (unsigned)vcol;
#pragma unroll
            for (int off = 1; off < 16; off <<= 1) {
              float ov = __shfl_xor(v, off, 64);
              unsigned oi = __shfl_xor(id, off, 64);
              if (ov > v || (ov == v && oi < id)) { v = ov; id = oi; }
            }
            if ((lane & 15) == 0) {
              unsigned kb = __float_as_uint(v);
              kb = (kb & 0x80000000u) ? ~kb : (kb | 0x80000000u);
              unsigned long long key = ((unsigned long long)kb << 32) | (unsigned)(~id);
              int b = mt * 16 + (lane >> 4) * 4 + r;
              unsigned long long cur = __hip_atomic_load(&P.amax[b], __ATOMIC_RELAXED,
                                                         __HIP_MEMORY_SCOPE_AGENT);
              if (cur < key) atomicMax(&P.amax[b], key);
            }
          }
        }
      }
      gsync(P.flags, ++ep * NB_);
    }
  }
}

// ============================ final batched output GEMM ============================
__global__ void __launch_bounds__(256, 2)
k_out(const _Float16* __restrict__ histH, const _Float16* __restrict__ histL,
      const _Float16* __restrict__ WoH, const _Float16* __restrict__ WoL,
      const float* __restrict__ bout, float* __restrict__ out) {
  int bid = blockIdx.x;          // 8000 = 500 nb x 16 mg
  int nb = bid / 16, mg = bid % 16;
  int w = threadIdx.x >> 6, lane = threadIdx.x & 63;
  int kof = (lane >> 4) * 8;
  int mt0 = mg * 8 + w * 2;
  f4 accH[2][4] = {}, accM[2][4] = {};
  for (int ks = 0; ks < 32; ++ks) {
    int kk = ks * 32 + kof;
    h8 Ah[2], Al[2];
#pragma unroll
    for (int mti = 0; mti < 2; ++mti) {
      int mt = mt0 + mti;
      if (mt < 126) {
        int m = mt * 16 + (lane & 15);
        int ii = m >> 5, b = m & 31;
        size_t ai = (size_t)(ii + 1) * 32768 + (size_t)b * 1024 + kk;
        Ah[mti] = *(const h8*)(histH + ai);
        Al[mti] = *(const h8*)(histL + ai);
      }
    }
#pragma unroll
    for (int nt = 0; nt < 4; ++nt) {
      int vcol = (nb * 4 + nt) * 16 + (lane & 15);
      h8 Bh = __builtin_nontemporal_load((const h8*)(WoH + (size_t)vcol * 1024 + kk));
      h8 Bl = __builtin_nontemporal_load((const h8*)(WoL + (size_t)vcol * 1024 + kk));
#pragma unroll
      for (int mti = 0; mti < 2; ++mti) {
        if (mt0 + mti < 126) {
          accH[mti][nt] = MFMA16(Ah[mti], Bh, accH[mti][nt]);
          accM[mti][nt] = MFMA16(Ah[mti], Bl, accM[mti][nt]);
          accM[mti][nt] = MFMA16(Al[mti], Bh, accM[mti][nt]);
        }
      }
    }
  }
#pragma unroll
  for (int mti = 0; mti < 2; ++mti) {
    int mt = mt0 + mti;
    if (mt >= 126) continue;
#pragma unroll
    for (int nt = 0; nt < 4; ++nt) {
      int vcol = (nb * 4 + nt) * 16 + (lane & 15);
      float bias = bout[vcol];
#pragma unroll
      for (int r = 0; r < 4; ++r) {
        int m = mt * 16 + (lane >> 4) * 4 + r;
        int ii = m >> 5, b = m & 31;
        out[(size_t)b * (Tt_ * V_) + (size_t)(ii + 1) * V_ + vcol] =
            accH[mti][nt][r] + accM[mti][nt][r] * (1.0f / 2048.0f) + bias;
      }
    }
  }
}

// ============================ host ============================

extern "C" void kernel_launch(void* const* d_in, const int* in_sizes, int n_in,
                              void* d_out, int out_size, void* d_ws, size_t ws_size,
                              hipStream_t stream) {
  const int*   itoks   = (const int*)d_in[0];
  const int*   target  = (const int*)d_in[1];
  const int*   tfm     = (const int*)d_in[2];
  const float* in_emb  = (const float*)d_in[3];
  const float* out_emb = (const float*)d_in[4];
  const float* encWih  = (const float*)d_in[5];
  const float* encWhh  = (const float*)d_in[6];
  const float* encbih  = (const float*)d_in[7];
  const float* encbhh  = (const float*)d_in[8];
  const float* decWih  = (const float*)d_in[9];
  const float* decWhh  = (const float*)d_in[10];
  const float* decbih  = (const float*)d_in[11];
  const float* decbhh  = (const float*)d_in[12];
  const float* Wout    = (const float*)d_in[13];
  const float* bout    = (const float*)d_in[14];
  float* out = (float*)d_out;

  char* ws = (char*)d_ws;
  size_t off = 0;
  auto alloc = [&](size_t bytes) { void* p = ws + off; off += (bytes + 255) & ~(size_t)255; return p; };
  _Float16* seqH  = (_Float16*)alloc((size_t)129 * 32768 * 2);
  _Float16* seqL  = (_Float16*)alloc((size_t)129 * 32768 * 2);
  _Float16* ehH   = (_Float16*)alloc((size_t)129 * 32768 * 2);
  _Float16* ehL   = (_Float16*)alloc((size_t)129 * 32768 * 2);
  _Float16* embH  = (_Float16*)alloc((size_t)128 * 32768 * 2);
  _Float16* embL  = (_Float16*)alloc((size_t)128 * 32768 * 2);
  _Float16* hist0H = (_Float16*)alloc((size_t)64 * 32768 * 2);
  _Float16* hist0L = (_Float16*)alloc((size_t)64 * 32768 * 2);
  _Float16* hist1H = (_Float16*)alloc((size_t)64 * 32768 * 2);
  _Float16* hist1L = (_Float16*)alloc((size_t)64 * 32768 * 2);
  float*    cb0   = (float*)alloc((size_t)32 * 1024 * 4);
  float*    cb1   = (float*)alloc((size_t)32 * 1024 * 4);
  _Float16* dWH   = (_Float16*)alloc((size_t)2 * 4096 * 2048 * 2);
  _Float16* dWL   = (_Float16*)alloc((size_t)2 * 4096 * 2048 * 2);
  _Float16* WoH   = (_Float16*)alloc((size_t)32000 * 1024 * 2);
  _Float16* WoL   = (_Float16*)alloc((size_t)32000 * 1024 * 2);
  unsigned long long* amax = (unsigned long long*)alloc(32 * 8);
  unsigned* encF = (unsigned*)alloc(NB_ * 4 * 4);
  unsigned* decF = (unsigned*)alloc(NB_ * 4 * 4);
  if (off > ws_size) return;

  k_prep0<<<1024, 256, 0, stream>>>(out, seqH, seqL, ehH, ehL, encF, decF);
  k_split_dec<<<2 * 4096, 256, 0, stream>>>(decWih, decWhh, dWH, dWL);
  k_split_wout<<<32000, 128, 0, stream>>>(Wout, WoH, WoL);
  k_emb<<<4096, 128, 0, stream>>>(itoks, in_emb, embH, embL);

  EP E;
  E.encWih = encWih; E.encWhh = encWhh; E.encbih = encbih; E.encbhh = encbhh;
  E.embH = embH; E.embL = embL;
  E.seqH = seqH; E.seqL = seqL; E.ehH = ehH; E.ehL = ehL;
  E.h0s0H = hist0H; E.h0s0L = hist0L; E.h1s0H = hist1H; E.h1s0L = hist1L;
  E.cb0 = cb0; E.cb1 = cb1; E.flags = encF;
  void* eargs[] = { &E };
  hipLaunchCooperativeKernel((void*)voice_enc, dim3(NB_), dim3(256), eargs, 0, stream);

  DP D;
  D.out_emb = out_emb; D.target = target; D.tfm = tfm;
  D.dWH = dWH; D.dWL = dWL; D.decbih = decbih; D.decbhh = decbhh;
  D.WoH = WoH; D.WoL = WoL; D.bout = bout;
  D.hist0H = hist0H; D.hist0L = hist0L; D.hist1H = hist1H; D.hist1L = hist1L;
  D.cb0 = cb0; D.cb1 = cb1; D.amax = amax; D.flags = decF;
  void* dargs[] = { &D };
  hipLaunchCooperativeKernel((void*)voice_dec, dim3(NB_), dim3(512), dargs, 0, stream);

  k_out<<<8000, 256, 0, stream>>>(hist1H, hist1L, WoH, WoL, bout, out);
}

// Round 7
// 10439.981 us; speedup vs baseline: 2.9228x; 1.0912x over previous
//
#include <hip/hip_runtime.h>
#include <cstdint>

#define S_  128
#define Tt_ 64
#define V_  32000
#define NB_ 256

typedef _Float16 h8 __attribute__((ext_vector_type(8)));
typedef float    f4 __attribute__((ext_vector_type(4)));

#define MFMA16(a,b,c) __builtin_amdgcn_mfma_f32_16x16x32_f16((a),(b),(c),0,0,0)

__device__ __forceinline__ void split8p(const float* __restrict__ p, h8& hi, h8& lo) {
  f4 a = *(const f4*)p;
  f4 b = *(const f4*)(p + 4);
#pragma unroll
  for (int i = 0; i < 4; i++) {
    _Float16 h0 = (_Float16)a[i];
    hi[i] = h0; lo[i] = (_Float16)((a[i] - (float)h0) * 2048.0f);
    _Float16 h1 = (_Float16)b[i];
    hi[i+4] = h1; lo[i+4] = (_Float16)((b[i] - (float)h1) * 2048.0f);
  }
}

// ---- fence-free device barrier (round-6 protocol, unchanged) ----
__device__ __forceinline__ void gsync(unsigned* flags, unsigned target) {
  asm volatile("s_waitcnt vmcnt(0)" ::: "memory");
  __syncthreads();
  int tid = threadIdx.x;
  if (tid == 0) {
    __hip_atomic_store(&flags[blockIdx.x * 4], target, __ATOMIC_RELAXED,
                       __HIP_MEMORY_SCOPE_AGENT);
  }
  if (tid < 64) {
    bool done;
    do {
      unsigned m = 0xFFFFFFFFu;
#pragma unroll
      for (int q = 0; q < 4; ++q) {
        unsigned f = __hip_atomic_load(&flags[(tid + q * 64) * 4], __ATOMIC_RELAXED,
                                       __HIP_MEMORY_SCOPE_AGENT);
        m = m < f ? m : f;
      }
      done = (bool)__all(m >= target);
      if (!done) __builtin_amdgcn_s_sleep(1);
    } while (!done);
  }
  __builtin_amdgcn_sched_barrier(0);
  __syncthreads();
  asm volatile("" ::: "memory");
}

__device__ __forceinline__ void store_h_pair(_Float16* __restrict__ oH,
                                             _Float16* __restrict__ oL,
                                             int b, int col0, int lane,
                                             _Float16 hh, _Float16 hl) {
  unsigned hs = (unsigned)__builtin_bit_cast(unsigned short, hh);
  unsigned ls = (unsigned)__builtin_bit_cast(unsigned short, hl);
  unsigned ph = (unsigned)__shfl_xor((int)hs, 32, 64);
  unsigned pl = (unsigned)__shfl_xor((int)ls, 32, 64);
  if (lane < 32) {
    unsigned hw = hs | (ph << 16);
    __hip_atomic_store((unsigned*)(oH + (size_t)b * 1024 + col0), hw,
                       __ATOMIC_RELAXED, __HIP_MEMORY_SCOPE_AGENT);
  } else {
    unsigned lw = pl | (ls << 16);
    __hip_atomic_store((unsigned*)(oL + (size_t)b * 1024 + col0), lw,
                       __ATOMIC_RELAXED, __HIP_MEMORY_SCOPE_AGENT);
  }
}

// ============================ prep kernels ============================

__global__ void k_prep0(float* __restrict__ out,
                        _Float16* __restrict__ seqH, _Float16* __restrict__ seqL,
                        _Float16* __restrict__ ehH, _Float16* __restrict__ ehL,
                        unsigned* __restrict__ encF, unsigned* __restrict__ decF) {
  int stride = gridDim.x * 256;
  for (unsigned idx = blockIdx.x * 256 + threadIdx.x; idx < 32u * V_; idx += stride) {
    unsigned b = idx / V_, v = idx - b * V_;
    out[(size_t)b * (Tt_ * V_) + v] = 0.0f;
  }
  for (unsigned idx = blockIdx.x * 256 + threadIdx.x; idx < 16384; idx += stride) {
    ((unsigned*)seqH)[idx] = 0u; ((unsigned*)seqL)[idx] = 0u;
    ((unsigned*)ehH)[idx]  = 0u; ((unsigned*)ehL)[idx]  = 0u;
  }
  for (unsigned idx = blockIdx.x * 256 + threadIdx.x; idx < NB_ * 4; idx += stride) {
    encF[idx] = 0u; decF[idx] = 0u;
  }
}

__global__ void k_split_dec(const float* __restrict__ decWih, const float* __restrict__ decWhh,
                            _Float16* __restrict__ WH, _Float16* __restrict__ WL) {
  int blk = blockIdx.x;               // 2*4096
  int tid = threadIdx.x;              // 256
  int l = blk >> 12, grow = blk & 4095;
  int k = tid * 8;
  const float* src = (k < 1024) ? (decWih + ((size_t)l * 4096 + grow) * 1024 + k)
                                : (decWhh + ((size_t)l * 4096 + grow) * 1024 + (k - 1024));
  h8 hi, lo;
  split8p(src, hi, lo);
  size_t d = ((size_t)l * 4096 + grow) * 2048 + k;
  *(h8*)(WH + d) = hi;
  *(h8*)(WL + d) = lo;
}

__global__ void k_split_wout(const float* __restrict__ Wout,
                             _Float16* __restrict__ WoH, _Float16* __restrict__ WoL) {
  int row = blockIdx.x;               // 32000
  int k = threadIdx.x * 8;            // 128 thr
  h8 hi, lo;
  split8p(Wout + (size_t)row * 1024 + k, hi, lo);
  *(h8*)(WoH + (size_t)row * 1024 + k) = hi;
  *(h8*)(WoL + (size_t)row * 1024 + k) = lo;
}

__global__ void k_emb(const int* __restrict__ itoks, const float* __restrict__ in_emb,
                      _Float16* __restrict__ embH, _Float16* __restrict__ embL) {
  int n = blockIdx.x;                 // 4096
  int b = n & 31, t = n >> 5;
  int tok = itoks[b * S_ + t];
  int k = threadIdx.x * 8;            // 128 thr
  h8 hi, lo;
  split8p(in_emb + (size_t)tok * 1024 + k, hi, lo);
  *(h8*)(embH + (size_t)n * 1024 + k) = hi;
  *(h8*)(embL + (size_t)n * 1024 + k) = lo;
}

// ============================ encoder (cooperative) ============================

struct EP {
  const float* encWih; const float* encWhh; const float* encbih; const float* encbhh;
  const _Float16 *embH, *embL;
  _Float16 *seqH, *seqL;    // 129 slots (layer0 h history)
  _Float16 *ehH, *ehL;      // 129 slots (layer1 h history)
  _Float16 *h0s0H, *h0s0L;  // hist0 slot 0 (cross-kernel)
  _Float16 *h1s0H, *h1s0L;  // hist1 slot 0 (cross-kernel)
  float *cb0, *cb1;
  unsigned* flags;
};

__device__ __forceinline__ int wadr(int row, int k) {
  return row * 2048 + ((((k << 1) ^ ((row & 7) << 4))) >> 1);
}

__device__ void preload_enc(const float* __restrict__ Wih, const float* __restrict__ Whh,
                            int blk, int tid, _Float16* sWH, _Float16* sWL) {
#pragma unroll 4
  for (int it = 0; it < 32; ++it) {
    int lin = (it * 256 + tid) * 4;
    int j16 = lin >> 11;
    int k   = lin & 2047;
    int g = j16 >> 2, u = j16 & 3;
    int grow = g * 1024 + blk * 4 + u;
    const float* src = (k < 1024) ? (Wih + (size_t)grow * 1024 + k)
                                  : (Whh + (size_t)grow * 1024 + (k - 1024));
    f4 x = *(const f4*)src;
#pragma unroll
    for (int q = 0; q < 4; q++) {
      _Float16 hh = (_Float16)x[q];
      sWH[wadr(j16, k + q)] = hh;
      sWL[wadr(j16, k + q)] = (_Float16)((x[q] - (float)hh) * 2048.0f);
    }
  }
}

// chunked-A version: 4 chunks x 4 ks; A loads batched (16 loads in flight)
__device__ void gates_enc(const _Float16* sWH, const _Float16* sWL, float* sScr,
                          const _Float16* __restrict__ xH, const _Float16* __restrict__ xL,
                          const _Float16* __restrict__ hHb, const _Float16* __restrict__ hLb,
                          int tid) {
  int w = tid >> 6, lane = tid & 63;
  int kbase = w * 512;
  bool xp = (w < 2);
  int j16 = lane & 15;
  const _Float16* aH = xp ? xH : (hHb - 1024);
  const _Float16* aL = xp ? xL : (hLb - 1024);
  f4 accH[2] = {}, accM[2] = {};
#pragma unroll
  for (int kc = 0; kc < 4; ++kc) {
    h8 Ah[4][2], Al[4][2];
#pragma unroll
    for (int k4 = 0; k4 < 4; ++k4) {
      int kk = kbase + (kc * 4 + k4) * 32 + (lane >> 4) * 8;
#pragma unroll
      for (int mt = 0; mt < 2; ++mt) {
        int brow = mt * 16 + (lane & 15);
        Ah[k4][mt] = *(const h8*)(aH + (size_t)brow * 1024 + kk);
        Al[k4][mt] = *(const h8*)(aL + (size_t)brow * 1024 + kk);
      }
    }
#pragma unroll
    for (int k4 = 0; k4 < 4; ++k4) {
      int kk = kbase + (kc * 4 + k4) * 32 + (lane >> 4) * 8;
      h8 Bh = *(const h8*)(sWH + wadr(j16, kk));
      h8 Bl = *(const h8*)(sWL + wadr(j16, kk));
#pragma unroll
      for (int mt = 0; mt < 2; ++mt) {
        accH[mt] = MFMA16(Ah[k4][mt], Bh, accH[mt]);
        accM[mt] = MFMA16(Ah[k4][mt], Bl, accM[mt]);
        accM[mt] = MFMA16(Al[k4][mt], Bh, accM[mt]);
      }
    }
  }
#pragma unroll
  for (int mt = 0; mt < 2; ++mt)
#pragma unroll
    for (int r = 0; r < 4; ++r) {
      int b = mt * 16 + (lane >> 4) * 4 + r;
      sScr[w * 544 + b * 17 + j16] = accH[mt][r] + accM[mt][r] * (1.0f / 2048.0f);
    }
}

__device__ void finish_enc(float* sScr, int blk, int tid,
                           const float* __restrict__ bih, const float* __restrict__ bhh,
                           float& c,
                           _Float16* __restrict__ oH, _Float16* __restrict__ oL,
                           _Float16* __restrict__ oH2, _Float16* __restrict__ oL2,
                           float* __restrict__ cOut) {
  __syncthreads();
  if (tid < 128) {
    int u = tid >> 5, b = tid & 31, lane = tid & 63;
    float g[4];
#pragma unroll
    for (int gg = 0; gg < 4; ++gg) {
      int j = gg * 4 + u;
      float s = sScr[0 * 544 + b * 17 + j] + sScr[1 * 544 + b * 17 + j]
              + sScr[2 * 544 + b * 17 + j] + sScr[3 * 544 + b * 17 + j];
      int grow = gg * 1024 + blk * 4 + u;
      g[gg] = s + bih[grow] + bhh[grow];
    }
    float ii = 1.0f / (1.0f + expf(-g[0]));
    float ff = 1.0f / (1.0f + expf(-g[1]));
    float gt = tanhf(g[2]);
    float oo = 1.0f / (1.0f + expf(-g[3]));
    c = ff * c + ii * gt;
    float hn = oo * tanhf(c);
    _Float16 hh = (_Float16)hn;
    _Float16 hl = (_Float16)((hn - (float)hh) * 2048.0f);
    int col0 = blk * 4 + (u & 2);
    store_h_pair(oH, oL, b, col0, lane, hh, hl);
    size_t ci = (size_t)b * 1024 + blk * 4 + u;
    if (oH2) { oH2[ci] = hh; oL2[ci] = hl; }
    if (cOut) cOut[ci] = c;
  }
}

__global__ void __launch_bounds__(256, 1) voice_enc(EP P) {
  __shared__ _Float16 sWH[16 * 2048];
  __shared__ _Float16 sWL[16 * 2048];
  __shared__ float    sScr[4 * 544];
  int blk = blockIdx.x, tid = threadIdx.x;
  float cA = 0.0f, cB = 0.0f;
  unsigned ep = 0;

  for (int l = 0; l < 2; ++l) {
    const float* Wih = P.encWih + (size_t)l * 4096 * 1024;
    const float* Whh = P.encWhh + (size_t)l * 4096 * 1024;
    const float* bih = P.encbih + (size_t)l * 4096;
    const float* bhh = P.encbhh + (size_t)l * 4096;
    preload_enc(Wih, Whh, blk, tid, sWH, sWL);
    __syncthreads();
    for (int t = 0; t < 128; ++t) {
      bool last = (t == 127);
      if (l == 0) {
        gates_enc(sWH, sWL, sScr,
                  P.embH + (size_t)t * 32768, P.embL + (size_t)t * 32768,
                  P.seqH + (size_t)t * 32768, P.seqL + (size_t)t * 32768, tid);
        finish_enc(sScr, blk, tid, bih, bhh, cA,
                   P.seqH + (size_t)(t + 1) * 32768, P.seqL + (size_t)(t + 1) * 32768,
                   last ? P.h0s0H : nullptr, last ? P.h0s0L : nullptr,
                   last ? P.cb0 : nullptr);
      } else {
        gates_enc(sWH, sWL, sScr,
                  P.seqH + (size_t)(t + 1) * 32768, P.seqL + (size_t)(t + 1) * 32768,
                  P.ehH + (size_t)t * 32768, P.ehL + (size_t)t * 32768, tid);
        finish_enc(sScr, blk, tid, bih, bhh, cB,
                   P.ehH + (size_t)(t + 1) * 32768, P.ehL + (size_t)(t + 1) * 32768,
                   last ? P.h1s0H : nullptr, last ? P.h1s0L : nullptr,
                   last ? P.cb1 : nullptr);
      }
      gsync(P.flags, ++ep * NB_);
    }
  }
}

// ============================ decoder (cooperative persistent) ============================

struct DP {
  const float* out_emb; const int* target; const int* tfm;
  const _Float16 *dWH, *dWL;
  const float *decbih, *decbhh;
  const _Float16 *WoH, *WoL;
  const float* bout;
  _Float16 *hist0H, *hist0L;        // 64 slots; slot i+1 = layer0 h of step i
  _Float16 *hist1H, *hist1L;        // 64 slots; slot i+1 = layer1 h of step i
  const float *cb0, *cb1;
  unsigned long long* amax;
  unsigned* flags;
};

// per-wave weight register set: 16 x h8 = 64 VGPR
struct WR { h8 h[8]; h8 l[8]; };

__device__ __forceinline__ void issue_w(const _Float16* __restrict__ WH,
                                        const _Float16* __restrict__ WL,
                                        int grow, int kbase, int lane, WR& r) {
#pragma unroll
  for (int ks = 0; ks < 8; ++ks) {
    int kk = kbase + ks * 32 + (lane >> 4) * 8;
    r.h[ks] = *(const h8*)(WH + (size_t)grow * 2048 + kk);
    r.l[ks] = *(const h8*)(WL + (size_t)grow * 2048 + kk);
  }
  __builtin_amdgcn_sched_barrier(0);   // pin the issue point; loads stay in flight
}

// MFMA phase using preloaded weights; A loads chunked by 2 ks.
// XM: 2 = x gathered from out_emb (tok0/tok1); 0 = x from split pair.
template <int XM>
__device__ void dcell_compute(const WR& wr,
                              const _Float16* __restrict__ xH, const _Float16* __restrict__ xL,
                              const float* __restrict__ out_emb, int tok0, int tok1,
                              const _Float16* __restrict__ hH, const _Float16* __restrict__ hL,
                              float* sScr, int w, int lane, int kbase) {
  bool xp = (w < 4);
  int j16 = lane & 15;
  const _Float16* aH = xp ? xH : (hH - 1024);
  const _Float16* aL = xp ? xL : (hL - 1024);
  f4 accH[2] = {}, accM[2] = {};
#pragma unroll
  for (int kc = 0; kc < 4; ++kc) {
    h8 Ah[2][2], Al[2][2];
#pragma unroll
    for (int k2 = 0; k2 < 2; ++k2) {
      int kk = kbase + (kc * 2 + k2) * 32 + (lane >> 4) * 8;
#pragma unroll
      for (int mt = 0; mt < 2; ++mt) {
        int brow = mt * 16 + (lane & 15);
        if (XM == 2 && xp) {
          int tk = mt ? tok1 : tok0;
          split8p(out_emb + (size_t)tk * 1024 + kk, Ah[k2][mt], Al[k2][mt]);
        } else {
          Ah[k2][mt] = *(const h8*)(aH + (size_t)brow * 1024 + kk);
          Al[k2][mt] = *(const h8*)(aL + (size_t)brow * 1024 + kk);
        }
      }
    }
#pragma unroll
    for (int k2 = 0; k2 < 2; ++k2) {
      const int ks = kc * 2 + k2;
#pragma unroll
      for (int mt = 0; mt < 2; ++mt) {
        accH[mt] = MFMA16(Ah[k2][mt], wr.h[ks], accH[mt]);
        accM[mt] = MFMA16(Ah[k2][mt], wr.l[ks], accM[mt]);
        accM[mt] = MFMA16(Al[k2][mt], wr.h[ks], accM[mt]);
      }
    }
  }
#pragma unroll
  for (int mt = 0; mt < 2; ++mt)
#pragma unroll
    for (int r = 0; r < 4; ++r) {
      int b = mt * 16 + (lane >> 4) * 4 + r;
      sScr[w * 544 + b * 17 + j16] = accH[mt][r] + accM[mt][r] * (1.0f / 2048.0f);
    }
}

__device__ void dcell_finish(float* sScr, int blk, int tid,
                             const float* __restrict__ bih, const float* __restrict__ bhh,
                             float& c,
                             _Float16* __restrict__ oH, _Float16* __restrict__ oL) {
  __syncthreads();
  if (tid < 128) {
    int u = tid >> 5, b = tid & 31, lanef = tid & 63;
    float g[4];
#pragma unroll
    for (int gg = 0; gg < 4; ++gg) {
      int j = gg * 4 + u;
      float s = 0.0f;
#pragma unroll
      for (int ww = 0; ww < 8; ++ww) s += sScr[ww * 544 + b * 17 + j];
      int growf = gg * 1024 + blk * 4 + u;
      g[gg] = s + bih[growf] + bhh[growf];
    }
    float ii = 1.0f / (1.0f + expf(-g[0]));
    float ff = 1.0f / (1.0f + expf(-g[1]));
    float gt = tanhf(g[2]);
    float oo = 1.0f / (1.0f + expf(-g[3]));
    c = ff * c + ii * gt;
    float hn = oo * tanhf(c);
    _Float16 hh = (_Float16)hn;
    _Float16 hl = (_Float16)((hn - (float)hh) * 2048.0f);
    int col0 = blk * 4 + (u & 2);
    store_h_pair(oH, oL, b, col0, lanef, hh, hl);
  }
}

__global__ void __launch_bounds__(512, 1) voice_dec(DP P) {
  __shared__ float sScr[8 * 544];
  int blk = blockIdx.x, tid = threadIdx.x;
  int w = tid >> 6, lane = tid & 63;
  int j16 = lane & 15;
  int grow = (j16 >> 2) * 1024 + blk * 4 + (j16 & 3);
  int kbase = w * 256;
  bool xp = (w < 4);
  unsigned ep = 0;
  float c0 = 0.0f, c1 = 0.0f;
  if (tid < 128) {
    int u = tid >> 5, b = tid & 31;
    size_t ci = (size_t)b * 1024 + blk * 4 + u;
    c0 = P.cb0[ci];
    c1 = P.cb1[ci];
  }
  const _Float16* W0H = P.dWH;
  const _Float16* W0L = P.dWL;
  const _Float16* W1H = P.dWH + (size_t)4096 * 2048;
  const _Float16* W1L = P.dWL + (size_t)4096 * 2048;

  WR wa, wb;
  issue_w(W0H, W0L, grow, kbase, lane, wa);     // cell0 weights for step 0

  for (int i = 0; i < 63; ++i) {
    _Float16* h0in   = P.hist0H + (size_t)i * 32768;       _Float16* h0inL  = P.hist0L + (size_t)i * 32768;
    _Float16* h0out  = P.hist0H + (size_t)(i + 1) * 32768; _Float16* h0outL = P.hist0L + (size_t)(i + 1) * 32768;
    _Float16* h1in   = P.hist1H + (size_t)i * 32768;       _Float16* h1inL  = P.hist1L + (size_t)i * 32768;
    _Float16* h1out  = P.hist1H + (size_t)(i + 1) * 32768; _Float16* h1outL = P.hist1L + (size_t)(i + 1) * 32768;

    // ---- phase A: layer0 cell (token-rule x), weights preloaded in wa ----
    int tok0 = 0, tok1 = 0;
    if (xp) {
      int b0 = lane & 15, b1 = 16 + (lane & 15);
      if (i == 0)              { tok0 = P.target[b0 * Tt_];     tok1 = P.target[b1 * Tt_]; }
      else if (P.tfm[i] > 0)   { tok0 = P.target[b0 * Tt_ + i]; tok1 = P.target[b1 * Tt_ + i]; }
      else {
        unsigned long long a0 = __hip_atomic_load(&P.amax[b0], __ATOMIC_RELAXED, __HIP_MEMORY_SCOPE_AGENT);
        unsigned long long a1 = __hip_atomic_load(&P.amax[b1], __ATOMIC_RELAXED, __HIP_MEMORY_SCOPE_AGENT);
        tok0 = (int)(~(unsigned)a0); tok1 = (int)(~(unsigned)a1);
      }
    }
    dcell_compute<2>(wa, nullptr, nullptr, P.out_emb, tok0, tok1,
                     h0in, h0inL, sScr, w, lane, kbase);
    issue_w(W1H, W1L, grow, kbase, lane, wb);   // prefetch cell1 weights (fly over barrier)
    dcell_finish(sScr, blk, tid, P.decbih, P.decbhh, c0, h0out, h0outL);
    gsync(P.flags, ++ep * NB_);

    // ---- phase B: layer1 cell, weights in wb; prefetch next step's cell0 ----
    if (blk == 0 && tid < 32)
      __hip_atomic_store(&P.amax[tid], 0ull, __ATOMIC_RELAXED, __HIP_MEMORY_SCOPE_AGENT);
    dcell_compute<0>(wb, h0out, h0outL, nullptr, 0, 0,
                     h1in, h1inL, sScr, w, lane, kbase);
    if (i < 62) issue_w(W0H, W0L, grow, kbase, lane, wa);
    dcell_finish(sScr, blk, tid, P.decbih + 4096, P.decbhh + 4096, c1, h1out, h1outL);
    gsync(P.flags, ++ep * NB_);

    // ---- phase C: argmax-only projection, only when step i+1 consumes it ----
    bool needC = (i < 62) && (P.tfm[i + 1] == 0);
    if (needC) {
      int vt = blk * 8 + w;
      if (vt < 2000) {
        int vcol = vt * 16 + (lane & 15);
        int kof = (lane >> 4) * 8;
        f4 accH[2] = {}, accM[2] = {};
#pragma unroll
        for (int kc = 0; kc < 8; ++kc) {
          h8 Bh[4], Bl[4], Ah[4][2], Al[4][2];
#pragma unroll
          for (int k4 = 0; k4 < 4; ++k4) {
            int kk = (kc * 4 + k4) * 32 + kof;
            Bh[k4] = *(const h8*)(P.WoH + (size_t)vcol * 1024 + kk);
            Bl[k4] = *(const h8*)(P.WoL + (size_t)vcol * 1024 + kk);
#pragma unroll
            for (int mt = 0; mt < 2; ++mt) {
              int brow = mt * 16 + (lane & 15);
              Ah[k4][mt] = *(const h8*)(h1out  + (size_t)brow * 1024 + kk);
              Al[k4][mt] = *(const h8*)(h1outL + (size_t)brow * 1024 + kk);
            }
          }
#pragma unroll
          for (int k4 = 0; k4 < 4; ++k4)
#pragma unroll
            for (int mt = 0; mt < 2; ++mt) {
              accH[mt] = MFMA16(Ah[k4][mt], Bh[k4], accH[mt]);
              accM[mt] = MFMA16(Ah[k4][mt], Bl[k4], accM[mt]);
              accM[mt] = MFMA16(Al[k4][mt], Bh[k4], accM[mt]);
            }
        }
        float bias = P.bout[vcol];
#pragma unroll
        for (int mt = 0; mt < 2; ++mt) {
          float vr[4];
#pragma unroll
          for (int r = 0; r < 4; ++r)
            vr[r] = accH[mt][r] + accM[mt][r] * (1.0f / 2048.0f) + bias;
#pragma unroll
          for (int r = 0; r < 4; ++r) {
            float v = vr[r];
            unsigned id = (unsigned)vcol;
#pragma unroll
            for (int off = 1; off < 16; off <<= 1) {
              float ov = __shfl_xor(v, off, 64);
              unsigned oi = __shfl_xor(id, off, 64);
              if (ov > v || (ov == v && oi < id)) { v = ov; id = oi; }
            }
            if ((lane & 15) == 0) {
              unsigned kb = __float_as_uint(v);
              kb = (kb & 0x80000000u) ? ~kb : (kb | 0x80000000u);
              unsigned long long key = ((unsigned long long)kb << 32) | (unsigned)(~id);
              int b = mt * 16 + (lane >> 4) * 4 + r;
              unsigned long long cur = __hip_atomic_load(&P.amax[b], __ATOMIC_RELAXED,
                                                         __HIP_MEMORY_SCOPE_AGENT);
              if (cur < key) atomicMax(&P.amax[b], key);
            }
          }
        }
      }
      gsync(P.flags, ++ep * NB_);
    }
  }
}

// ============================ final batched output GEMM ============================
__global__ void __launch_bounds__(256, 2)
k_out(const _Float16* __restrict__ histH, const _Float16* __restrict__ histL,
      const _Float16* __restrict__ WoH, const _Float16* __restrict__ WoL,
      const float* __restrict__ bout, float* __restrict__ out) {
  int bid = blockIdx.x;          // 8000 = 500 nb x 16 mg
  int nb = bid / 16, mg = bid % 16;
  int w = threadIdx.x >> 6, lane = threadIdx.x & 63;
  int kof = (lane >> 4) * 8;
  int mt0 = mg * 8 + w * 2;
  f4 accH[2][4] = {}, accM[2][4] = {};
  for (int ks = 0; ks < 32; ++ks) {
    int kk = ks * 32 + kof;
    h8 Ah[2], Al[2];
#pragma unroll
    for (int mti = 0; mti < 2; ++mti) {
      int mt = mt0 + mti;
      if (mt < 126) {
        int m = mt * 16 + (lane & 15);
        int ii = m >> 5, b = m & 31;
        size_t ai = (size_t)(ii + 1) * 32768 + (size_t)b * 1024 + kk;
        Ah[mti] = *(const h8*)(histH + ai);
        Al[mti] = *(const h8*)(histL + ai);
      }
    }
#pragma unroll
    for (int nt = 0; nt < 4; ++nt) {
      int vcol = (nb * 4 + nt) * 16 + (lane & 15);
      h8 Bh = __builtin_nontemporal_load((const h8*)(WoH + (size_t)vcol * 1024 + kk));
      h8 Bl = __builtin_nontemporal_load((const h8*)(WoL + (size_t)vcol * 1024 + kk));
#pragma unroll
      for (int mti = 0; mti < 2; ++mti) {
        if (mt0 + mti < 126) {
          accH[mti][nt] = MFMA16(Ah[mti], Bh, accH[mti][nt]);
          accM[mti][nt] = MFMA16(Ah[mti], Bl, accM[mti][nt]);
          accM[mti][nt] = MFMA16(Al[mti], Bh, accM[mti][nt]);
        }
      }
    }
  }
#pragma unroll
  for (int mti = 0; mti < 2; ++mti) {
    int mt = mt0 + mti;
    if (mt >= 126) continue;
#pragma unroll
    for (int nt = 0; nt < 4; ++nt) {
      int vcol = (nb * 4 + nt) * 16 + (lane & 15);
      float bias = bout[vcol];
#pragma unroll
      for (int r = 0; r < 4; ++r) {
        int m = mt * 16 + (lane >> 4) * 4 + r;
        int ii = m >> 5, b = m & 31;
        out[(size_t)b * (Tt_ * V_) + (size_t)(ii + 1) * V_ + vcol] =
            accH[mti][nt][r] + accM[mti][nt][r] * (1.0f / 2048.0f) + bias;
      }
    }
  }
}

// ============================ host ============================

extern "C" void kernel_launch(void* const* d_in, const int* in_sizes, int n_in,
                              void* d_out, int out_size, void* d_ws, size_t ws_size,
                              hipStream_t stream) {
  const int*   itoks   = (const int*)d_in[0];
  const int*   target  = (const int*)d_in[1];
  const int*   tfm     = (const int*)d_in[2];
  const float* in_emb  = (const float*)d_in[3];
  const float* out_emb = (const float*)d_in[4];
  const float* encWih  = (const float*)d_in[5];
  const float* encWhh  = (const float*)d_in[6];
  const float* encbih  = (const float*)d_in[7];
  const float* encbhh  = (const float*)d_in[8];
  const float* decWih  = (const float*)d_in[9];
  const float* decWhh  = (const float*)d_in[10];
  const float* decbih  = (const float*)d_in[11];
  const float* decbhh  = (const float*)d_in[12];
  const float* Wout    = (const float*)d_in[13];
  const float* bout    = (const float*)d_in[14];
  float* out = (float*)d_out;

  char* ws = (char*)d_ws;
  size_t off = 0;
  auto alloc = [&](size_t bytes) { void* p = ws + off; off += (bytes + 255) & ~(size_t)255; return p; };
  _Float16* seqH  = (_Float16*)alloc((size_t)129 * 32768 * 2);
  _Float16* seqL  = (_Float16*)alloc((size_t)129 * 32768 * 2);
  _Float16* ehH   = (_Float16*)alloc((size_t)129 * 32768 * 2);
  _Float16* ehL   = (_Float16*)alloc((size_t)129 * 32768 * 2);
  _Float16* embH  = (_Float16*)alloc((size_t)128 * 32768 * 2);
  _Float16* embL  = (_Float16*)alloc((size_t)128 * 32768 * 2);
  _Float16* hist0H = (_Float16*)alloc((size_t)64 * 32768 * 2);
  _Float16* hist0L = (_Float16*)alloc((size_t)64 * 32768 * 2);
  _Float16* hist1H = (_Float16*)alloc((size_t)64 * 32768 * 2);
  _Float16* hist1L = (_Float16*)alloc((size_t)64 * 32768 * 2);
  float*    cb0   = (float*)alloc((size_t)32 * 1024 * 4);
  float*    cb1   = (float*)alloc((size_t)32 * 1024 * 4);
  _Float16* dWH   = (_Float16*)alloc((size_t)2 * 4096 * 2048 * 2);
  _Float16* dWL   = (_Float16*)alloc((size_t)2 * 4096 * 2048 * 2);
  _Float16* WoH   = (_Float16*)alloc((size_t)32000 * 1024 * 2);
  _Float16* WoL   = (_Float16*)alloc((size_t)32000 * 1024 * 2);
  unsigned long long* amax = (unsigned long long*)alloc(32 * 8);
  unsigned* encF = (unsigned*)alloc(NB_ * 4 * 4);
  unsigned* decF = (unsigned*)alloc(NB_ * 4 * 4);
  if (off > ws_size) return;

  k_prep0<<<1024, 256, 0, stream>>>(out, seqH, seqL, ehH, ehL, encF, decF);
  k_split_dec<<<2 * 4096, 256, 0, stream>>>(decWih, decWhh, dWH, dWL);
  k_split_wout<<<32000, 128, 0, stream>>>(Wout, WoH, WoL);
  k_emb<<<4096, 128, 0, stream>>>(itoks, in_emb, embH, embL);

  EP E;
  E.encWih = encWih; E.encWhh = encWhh; E.encbih = encbih; E.encbhh = encbhh;
  E.embH = embH; E.embL = embL;
  E.seqH = seqH; E.seqL = seqL; E.ehH = ehH; E.ehL = ehL;
  E.h0s0H = hist0H; E.h0s0L = hist0L; E.h1s0H = hist1H; E.h1s0L = hist1L;
  E.cb0 = cb0; E.cb1 = cb1; E.flags = encF;
  void* eargs[] = { &E };
  hipLaunchCooperativeKernel((void*)voice_enc, dim3(NB_), dim3(256), eargs, 0, stream);

  DP D;
  D.out_emb = out_emb; D.target = target; D.tfm = tfm;
  D.dWH = dWH; D.dWL = dWL; D.decbih = decbih; D.decbhh = decbhh;
  D.WoH = WoH; D.WoL = WoL; D.bout = bout;
  D.hist0H = hist0H; D.hist0L = hist0L; D.hist1H = hist1H; D.hist1L = hist1L;
  D.cb0 = cb0; D.cb1 = cb1; D.amax = amax; D.flags = decF;
  void* dargs[] = { &D };
  hipLaunchCooperativeKernel((void*)voice_dec, dim3(NB_), dim3(512), dargs, 0, stream);

  k_out<<<8000, 256, 0, stream>>>(hist1H, hist1L, WoH, WoL, bout, out);
}

// Round 8
// 7892.920 us; speedup vs baseline: 3.8660x; 1.3227x over previous
//
#include <hip/hip_runtime.h>
#include <cstdint>

#define S_  128
#define Tt_ 64
#define V_  32000
#define NB_ 256

typedef _Float16 h8 __attribute__((ext_vector_type(8)));
typedef float    f4 __attribute__((ext_vector_type(4)));

#define MFMA16(a,b,c) __builtin_amdgcn_mfma_f32_16x16x32_f16((a),(b),(c),0,0,0)

__device__ __forceinline__ void split8p(const float* __restrict__ p, h8& hi, h8& lo) {
  f4 a = *(const f4*)p;
  f4 b = *(const f4*)(p + 4);
#pragma unroll
  for (int i = 0; i < 4; i++) {
    _Float16 h0 = (_Float16)a[i];
    hi[i] = h0; lo[i] = (_Float16)((a[i] - (float)h0) * 2048.0f);
    _Float16 h1 = (_Float16)b[i];
    hi[i+4] = h1; lo[i+4] = (_Float16)((b[i] - (float)h1) * 2048.0f);
  }
}

// ---- fence-free device barrier (round-6 protocol) ----
__device__ __forceinline__ void gsync(unsigned* flags, unsigned target) {
  asm volatile("s_waitcnt vmcnt(0)" ::: "memory");
  __syncthreads();
  int tid = threadIdx.x;
  if (tid == 0) {
    __hip_atomic_store(&flags[blockIdx.x * 4], target, __ATOMIC_RELAXED,
                       __HIP_MEMORY_SCOPE_AGENT);
  }
  if (tid < 64) {
    bool done;
    do {
      unsigned m = 0xFFFFFFFFu;
#pragma unroll
      for (int q = 0; q < 4; ++q) {
        unsigned f = __hip_atomic_load(&flags[(tid + q * 64) * 4], __ATOMIC_RELAXED,
                                       __HIP_MEMORY_SCOPE_AGENT);
        m = m < f ? m : f;
      }
      done = (bool)__all(m >= target);
      if (!done) __builtin_amdgcn_s_sleep(1);
    } while (!done);
  }
  __builtin_amdgcn_sched_barrier(0);
  __syncthreads();
  asm volatile("" ::: "memory");
}

__device__ __forceinline__ void store_h_pair(_Float16* __restrict__ oH,
                                             _Float16* __restrict__ oL,
                                             int b, int col0, int lane,
                                             _Float16 hh, _Float16 hl) {
  unsigned hs = (unsigned)__builtin_bit_cast(unsigned short, hh);
  unsigned ls = (unsigned)__builtin_bit_cast(unsigned short, hl);
  unsigned ph = (unsigned)__shfl_xor((int)hs, 32, 64);
  unsigned pl = (unsigned)__shfl_xor((int)ls, 32, 64);
  if (lane < 32) {
    unsigned hw = hs | (ph << 16);
    __hip_atomic_store((unsigned*)(oH + (size_t)b * 1024 + col0), hw,
                       __ATOMIC_RELAXED, __HIP_MEMORY_SCOPE_AGENT);
  } else {
    unsigned lw = pl | (ls << 16);
    __hip_atomic_store((unsigned*)(oL + (size_t)b * 1024 + col0), lw,
                       __ATOMIC_RELAXED, __HIP_MEMORY_SCOPE_AGENT);
  }
}

// ============================ prep kernels ============================

__global__ void k_prep0(float* __restrict__ out,
                        _Float16* __restrict__ seqH, _Float16* __restrict__ seqL,
                        _Float16* __restrict__ ehH, _Float16* __restrict__ ehL,
                        unsigned* __restrict__ encF, unsigned* __restrict__ decF) {
  int stride = gridDim.x * 256;
  for (unsigned idx = blockIdx.x * 256 + threadIdx.x; idx < 32u * V_; idx += stride) {
    unsigned b = idx / V_, v = idx - b * V_;
    out[(size_t)b * (Tt_ * V_) + v] = 0.0f;
  }
  for (unsigned idx = blockIdx.x * 256 + threadIdx.x; idx < 16384; idx += stride) {
    ((unsigned*)seqH)[idx] = 0u; ((unsigned*)seqL)[idx] = 0u;
    ((unsigned*)ehH)[idx]  = 0u; ((unsigned*)ehL)[idx]  = 0u;
  }
  for (unsigned idx = blockIdx.x * 256 + threadIdx.x; idx < NB_ * 4; idx += stride) {
    encF[idx] = 0u; decF[idx] = 0u;
  }
}

// decoder weights -> wave-linear tiles: W2[l][blk][w][ks][lane*8], contiguous per wave
__global__ void k_dw2(const float* __restrict__ decWih, const float* __restrict__ decWhh,
                      _Float16* __restrict__ W2H, _Float16* __restrict__ W2L) {
  int b = blockIdx.x;            // 8192 = 2 l x 256 blk x 16 w
  int l = b >> 12, rem = b & 4095;
  int blk = rem >> 4, w = rem & 15;
  int t = threadIdx.x;           // 256: 4 ks x 64 lanes
  int ks = t >> 6, lane = t & 63;
  int j16 = lane & 15;
  int grow = (j16 >> 2) * 1024 + blk * 4 + (j16 & 3);
  int kk = w * 128 + ks * 32 + (lane >> 4) * 8;
  const float* src = (kk < 1024)
      ? decWih + ((size_t)l * 4096 + grow) * 1024 + kk
      : decWhh + ((size_t)l * 4096 + grow) * 1024 + (kk - 1024);
  h8 hi, lo; split8p(src, hi, lo);
  size_t d = ((((size_t)l * 256 + blk) * 16 + w) * 4 + ks) * 512 + lane * 8;
  *(h8*)(W2H + d) = hi;
  *(h8*)(W2L + d) = lo;
}

// W_out -> vt tiles: Wo2[vt][ks][lane*8]
__global__ void k_wo2(const float* __restrict__ Wout,
                      _Float16* __restrict__ Wo2H, _Float16* __restrict__ Wo2L) {
  int b = blockIdx.x;            // 16000 = 2000 vt x 8
  int vt = b >> 3, kb = (b & 7) * 4;
  int t = threadIdx.x;
  int ks = kb + (t >> 6), lane = t & 63;
  int vcol = vt * 16 + (lane & 15);
  int kk = ks * 32 + (lane >> 4) * 8;
  h8 hi, lo; split8p(Wout + (size_t)vcol * 1024 + kk, hi, lo);
  size_t d = ((size_t)vt * 32 + ks) * 512 + lane * 8;
  *(h8*)(Wo2H + d) = hi;
  *(h8*)(Wo2L + d) = lo;
}

__global__ void k_emb(const int* __restrict__ itoks, const float* __restrict__ in_emb,
                      _Float16* __restrict__ embH, _Float16* __restrict__ embL) {
  int n = blockIdx.x;                 // 4096
  int b = n & 31, t = n >> 5;
  int tok = itoks[b * S_ + t];
  int k = threadIdx.x * 8;            // 128 thr
  h8 hi, lo;
  split8p(in_emb + (size_t)tok * 1024 + k, hi, lo);
  *(h8*)(embH + (size_t)n * 1024 + k) = hi;
  *(h8*)(embL + (size_t)n * 1024 + k) = lo;
}

// ============================ encoder (cooperative, diagonal 2-layer) ============================

struct EP {
  const float* encWih; const float* encWhh; const float* encbih; const float* encbhh;
  const _Float16 *embH, *embL;
  _Float16 *seqH, *seqL;    // 129 slots (layer0 h history)
  _Float16 *ehH, *ehL;      // 129 slots (layer1 h history)
  _Float16 *h0s0H, *h0s0L;  // hist0 slot 0 (cross-kernel)
  _Float16 *h1s0H, *h1s0L;  // hist1 slot 0 (cross-kernel)
  float *cb0, *cb1;
  unsigned* flags;
};

__device__ __forceinline__ int wadr(int row, int k) {
  return row * 2048 + ((((k << 1) ^ ((row & 7) << 4))) >> 1);
}

// layer0 weight preload into LDS (512 threads)
__device__ void preload_enc(const float* __restrict__ Wih, const float* __restrict__ Whh,
                            int blk, int tid, _Float16* sWH, _Float16* sWL) {
#pragma unroll 4
  for (int it = 0; it < 16; ++it) {
    int lin = (it * 512 + tid) * 4;
    int j16 = lin >> 11;
    int k   = lin & 2047;
    int g = j16 >> 2, u = j16 & 3;
    int grow = g * 1024 + blk * 4 + u;
    const float* src = (k < 1024) ? (Wih + (size_t)grow * 1024 + k)
                                  : (Whh + (size_t)grow * 1024 + (k - 1024));
    f4 x = *(const f4*)src;
#pragma unroll
    for (int q = 0; q < 4; q++) {
      _Float16 hh = (_Float16)x[q];
      sWH[wadr(j16, k + q)] = hh;
      sWL[wadr(j16, k + q)] = (_Float16)((x[q] - (float)hh) * 2048.0f);
    }
  }
}

// layer0 gate GEMM (waves 0-3, LDS weights), chunked A (4x4)
__device__ void gates_enc(const _Float16* sWH, const _Float16* sWL, float* sScr,
                          const _Float16* __restrict__ xH, const _Float16* __restrict__ xL,
                          const _Float16* __restrict__ hHb, const _Float16* __restrict__ hLb,
                          int tid) {
  int w = tid >> 6, lane = tid & 63;
  int kbase = w * 512;
  bool xp = (w < 2);
  int j16 = lane & 15;
  const _Float16* aH = xp ? xH : (hHb - 1024);
  const _Float16* aL = xp ? xL : (hLb - 1024);
  f4 accH[2] = {}, accM[2] = {};
#pragma unroll
  for (int kc = 0; kc < 4; ++kc) {
    h8 Ah[4][2], Al[4][2];
#pragma unroll
    for (int k4 = 0; k4 < 4; ++k4) {
      int kk = kbase + (kc * 4 + k4) * 32 + (lane >> 4) * 8;
#pragma unroll
      for (int mt = 0; mt < 2; ++mt) {
        int brow = mt * 16 + (lane & 15);
        Ah[k4][mt] = *(const h8*)(aH + (size_t)brow * 1024 + kk);
        Al[k4][mt] = *(const h8*)(aL + (size_t)brow * 1024 + kk);
      }
    }
#pragma unroll
    for (int k4 = 0; k4 < 4; ++k4) {
      int kk = kbase + (kc * 4 + k4) * 32 + (lane >> 4) * 8;
      h8 Bh = *(const h8*)(sWH + wadr(j16, kk));
      h8 Bl = *(const h8*)(sWL + wadr(j16, kk));
#pragma unroll
      for (int mt = 0; mt < 2; ++mt) {
        accH[mt] = MFMA16(Ah[k4][mt], Bh, accH[mt]);
        accM[mt] = MFMA16(Ah[k4][mt], Bl, accM[mt]);
        accM[mt] = MFMA16(Al[k4][mt], Bh, accM[mt]);
      }
    }
  }
#pragma unroll
  for (int mt = 0; mt < 2; ++mt)
#pragma unroll
    for (int r = 0; r < 4; ++r) {
      int b = mt * 16 + (lane >> 4) * 4 + r;
      sScr[w * 544 + b * 17 + j16] = accH[mt][r] + accM[mt][r] * (1.0f / 2048.0f);
    }
}

// layer1 gate GEMM (waves 4-7, weights streamed fp32 + inline split)
__device__ void gates_enc1(const float* __restrict__ Wx, const float* __restrict__ Wh,
                           float* sScr,
                           const _Float16* __restrict__ xH, const _Float16* __restrict__ xL,
                           const _Float16* __restrict__ hHb, const _Float16* __restrict__ hLb,
                           int blk, int tid) {
  int w = tid >> 6, lane = tid & 63;
  int ws = w - 4;
  int kbase = ws * 512;
  bool xp = (ws < 2);
  int j16 = lane & 15;
  int grow = (j16 >> 2) * 1024 + blk * 4 + (j16 & 3);
  const _Float16* aH = xp ? xH : (hHb - 1024);
  const _Float16* aL = xp ? xL : (hLb - 1024);
  f4 accH[2] = {}, accM[2] = {};
#pragma unroll
  for (int kc = 0; kc < 4; ++kc) {
    h8 Ah[4][2], Al[4][2];
#pragma unroll
    for (int k4 = 0; k4 < 4; ++k4) {
      int kk = kbase + (kc * 4 + k4) * 32 + (lane >> 4) * 8;
#pragma unroll
      for (int mt = 0; mt < 2; ++mt) {
        int brow = mt * 16 + (lane & 15);
        Ah[k4][mt] = *(const h8*)(aH + (size_t)brow * 1024 + kk);
        Al[k4][mt] = *(const h8*)(aL + (size_t)brow * 1024 + kk);
      }
    }
#pragma unroll
    for (int k4 = 0; k4 < 4; ++k4) {
      int kk = kbase + (kc * 4 + k4) * 32 + (lane >> 4) * 8;
      const float* src = xp ? (Wx + (size_t)grow * 1024 + kk)
                            : (Wh + (size_t)grow * 1024 + (kk - 1024));
      h8 Bh, Bl;
      split8p(src, Bh, Bl);
#pragma unroll
      for (int mt = 0; mt < 2; ++mt) {
        accH[mt] = MFMA16(Ah[k4][mt], Bh, accH[mt]);
        accM[mt] = MFMA16(Ah[k4][mt], Bl, accM[mt]);
        accM[mt] = MFMA16(Al[k4][mt], Bh, accM[mt]);
      }
    }
  }
#pragma unroll
  for (int mt = 0; mt < 2; ++mt)
#pragma unroll
    for (int r = 0; r < 4; ++r) {
      int b = mt * 16 + (lane >> 4) * 4 + r;
      sScr[w * 544 + b * 17 + j16] = accH[mt][r] + accM[mt][r] * (1.0f / 2048.0f);
    }
}

// cell finish (caller must __syncthreads() first); reads 4 partial slices at sScr
__device__ void finish_enc(float* sScr, int blk, int tid,
                           const float* __restrict__ bih, const float* __restrict__ bhh,
                           float& c,
                           _Float16* __restrict__ oH, _Float16* __restrict__ oL,
                           _Float16* __restrict__ oH2, _Float16* __restrict__ oL2,
                           float* __restrict__ cOut) {
  if (tid >= 0 && tid < 128) {
    int u = tid >> 5, b = tid & 31, lane = tid & 63;
    float g[4];
#pragma unroll
    for (int gg = 0; gg < 4; ++gg) {
      int j = gg * 4 + u;
      float s = sScr[0 * 544 + b * 17 + j] + sScr[1 * 544 + b * 17 + j]
              + sScr[2 * 544 + b * 17 + j] + sScr[3 * 544 + b * 17 + j];
      int grow = gg * 1024 + blk * 4 + u;
      g[gg] = s + bih[grow] + bhh[grow];
    }
    float ii = 1.0f / (1.0f + expf(-g[0]));
    float ff = 1.0f / (1.0f + expf(-g[1]));
    float gt = tanhf(g[2]);
    float oo = 1.0f / (1.0f + expf(-g[3]));
    c = ff * c + ii * gt;
    float hn = oo * tanhf(c);
    _Float16 hh = (_Float16)hn;
    _Float16 hl = (_Float16)((hn - (float)hh) * 2048.0f);
    int col0 = blk * 4 + (u & 2);
    store_h_pair(oH, oL, b, col0, lane, hh, hl);
    size_t ci = (size_t)b * 1024 + blk * 4 + u;
    if (oH2) { oH2[ci] = hh; oL2[ci] = hl; }
    if (cOut) cOut[ci] = c;
  }
}

__global__ void __launch_bounds__(512, 2) voice_enc(EP P) {
  __shared__ _Float16 sWH[16 * 2048];   // 64 KB (layer0)
  __shared__ _Float16 sWL[16 * 2048];   // 64 KB
  __shared__ float    sScr[8 * 544];    // 17.4 KB
  int blk = blockIdx.x, tid = threadIdx.x;
  int w = tid >> 6;
  float cA = 0.0f, cB = 0.0f;
  unsigned ep = 0;

  preload_enc(P.encWih, P.encWhh, blk, tid, sWH, sWL);
  __syncthreads();
  const float* Wx1 = P.encWih + (size_t)4096 * 1024;
  const float* Wh1 = P.encWhh + (size_t)4096 * 1024;

  for (int t = 0; t <= 128; ++t) {
    if (w < 4) {
      if (t < 128)
        gates_enc(sWH, sWL, sScr,
                  P.embH + (size_t)t * 32768, P.embL + (size_t)t * 32768,
                  P.seqH + (size_t)t * 32768, P.seqL + (size_t)t * 32768, tid);
    } else {
      if (t >= 1)
        gates_enc1(Wx1, Wh1, sScr,
                   P.seqH + (size_t)t * 32768, P.seqL + (size_t)t * 32768,
                   P.ehH + (size_t)(t - 1) * 32768, P.ehL + (size_t)(t - 1) * 32768,
                   blk, tid);
    }
    __syncthreads();
    if (t < 128 && tid < 256) {
      bool last = (t == 127);
      finish_enc(sScr, blk, tid, P.encbih, P.encbhh, cA,
                 P.seqH + (size_t)(t + 1) * 32768, P.seqL + (size_t)(t + 1) * 32768,
                 last ? P.h0s0H : nullptr, last ? P.h0s0L : nullptr,
                 last ? P.cb0 : nullptr);
    }
    if (t >= 1 && tid >= 256) {
      bool last = (t == 128);
      finish_enc(sScr + 4 * 544, blk, tid - 256, P.encbih + 4096, P.encbhh + 4096, cB,
                 P.ehH + (size_t)t * 32768, P.ehL + (size_t)t * 32768,
                 last ? P.h1s0H : nullptr, last ? P.h1s0L : nullptr,
                 last ? P.cb1 : nullptr);
    }
    gsync(P.flags, ++ep * NB_);
  }
}

// ============================ decoder (cooperative, 1024 threads) ============================

struct DP {
  const float* out_emb; const int* target; const int* tfm;
  const _Float16 *dW2H, *dW2L;      // wave-linear tiles
  const float *decbih, *decbhh;
  const _Float16 *Wo2H, *Wo2L;      // vt tiles
  const float* bout;
  _Float16 *hist0H, *hist0L;        // 64 slots
  _Float16 *hist1H, *hist1L;        // 64 slots
  const float *cb0, *cb1;
  unsigned long long* amax;
  unsigned* flags;
};

// one LSTM cell GEMM on 16 waves (K=128/wave), linear weight tiles
template <int XM>
__device__ void dcell16(const _Float16* __restrict__ W2H, const _Float16* __restrict__ W2L,
                        const _Float16* __restrict__ xH, const _Float16* __restrict__ xL,
                        const float* __restrict__ out_emb, int tok0, int tok1,
                        const _Float16* __restrict__ hH, const _Float16* __restrict__ hL,
                        float* sScr, int blk, int tid) {
  int w = tid >> 6, lane = tid & 63;
  int j16 = lane & 15;
  int kbase = w * 128;
  bool xp = (w < 8);
  const _Float16* aH = xp ? xH : (hH - 1024);
  const _Float16* aL = xp ? xL : (hL - 1024);
  const _Float16* wbH = W2H + (((size_t)(blk * 16 + w)) * 4) * 512 + lane * 8;
  const _Float16* wbL = W2L + (((size_t)(blk * 16 + w)) * 4) * 512 + lane * 8;
  h8 Bh[4], Bl[4];
#pragma unroll
  for (int ks = 0; ks < 4; ++ks) {
    Bh[ks] = *(const h8*)(wbH + ks * 512);
    Bl[ks] = *(const h8*)(wbL + ks * 512);
  }
  f4 accH[2] = {}, accM[2] = {};
#pragma unroll
  for (int kc = 0; kc < 2; ++kc) {
    h8 Ah[2][2], Al[2][2];
#pragma unroll
    for (int k2 = 0; k2 < 2; ++k2) {
      int kk = kbase + (kc * 2 + k2) * 32 + (lane >> 4) * 8;
#pragma unroll
      for (int mt = 0; mt < 2; ++mt) {
        int brow = mt * 16 + j16;
        if (XM == 2 && xp) {
          int tk = mt ? tok1 : tok0;
          split8p(out_emb + (size_t)tk * 1024 + kk, Ah[k2][mt], Al[k2][mt]);
        } else {
          Ah[k2][mt] = *(const h8*)(aH + (size_t)brow * 1024 + kk);
          Al[k2][mt] = *(const h8*)(aL + (size_t)brow * 1024 + kk);
        }
      }
    }
#pragma unroll
    for (int k2 = 0; k2 < 2; ++k2) {
      int ks = kc * 2 + k2;
#pragma unroll
      for (int mt = 0; mt < 2; ++mt) {
        accH[mt] = MFMA16(Ah[k2][mt], Bh[ks], accH[mt]);
        accM[mt] = MFMA16(Ah[k2][mt], Bl[ks], accM[mt]);
        accM[mt] = MFMA16(Al[k2][mt], Bh[ks], accM[mt]);
      }
    }
  }
#pragma unroll
  for (int mt = 0; mt < 2; ++mt)
#pragma unroll
    for (int r = 0; r < 4; ++r) {
      int b = mt * 16 + (lane >> 4) * 4 + r;
      sScr[w * 544 + b * 17 + j16] = accH[mt][r] + accM[mt][r] * (1.0f / 2048.0f);
    }
}

__device__ void dcell_finish16(float* sScr, int blk, int tid,
                               const float* __restrict__ bih, const float* __restrict__ bhh,
                               float& c,
                               _Float16* __restrict__ oH, _Float16* __restrict__ oL) {
  __syncthreads();
  if (tid < 128) {
    int u = tid >> 5, b = tid & 31, lanef = tid & 63;
    float g[4];
#pragma unroll
    for (int gg = 0; gg < 4; ++gg) {
      int j = gg * 4 + u;
      float s = 0.0f;
#pragma unroll
      for (int ww = 0; ww < 16; ++ww) s += sScr[ww * 544 + b * 17 + j];
      int growf = gg * 1024 + blk * 4 + u;
      g[gg] = s + bih[growf] + bhh[growf];
    }
    float ii = 1.0f / (1.0f + expf(-g[0]));
    float ff = 1.0f / (1.0f + expf(-g[1]));
    float gt = tanhf(g[2]);
    float oo = 1.0f / (1.0f + expf(-g[3]));
    c = ff * c + ii * gt;
    float hn = oo * tanhf(c);
    _Float16 hh = (_Float16)hn;
    _Float16 hl = (_Float16)((hn - (float)hh) * 2048.0f);
    int col0 = blk * 4 + (u & 2);
    store_h_pair(oH, oL, b, col0, lanef, hh, hl);
  }
}

__global__ void __launch_bounds__(1024, 4) voice_dec(DP P) {
  __shared__ float sScr[16 * 544];      // 34.8 KB (reused by phase C: 16*512 floats)
  int blk = blockIdx.x, tid = threadIdx.x;
  int w = tid >> 6, lane = tid & 63;
  unsigned ep = 0;
  float c0 = 0.0f, c1 = 0.0f;
  if (tid < 128) {
    int u = tid >> 5, b = tid & 31;
    size_t ci = (size_t)b * 1024 + blk * 4 + u;
    c0 = P.cb0[ci];
    c1 = P.cb1[ci];
  }
  const _Float16* W0H = P.dW2H;
  const _Float16* W0L = P.dW2L;
  const _Float16* W1H = P.dW2H + (size_t)8388608;
  const _Float16* W1L = P.dW2L + (size_t)8388608;

  for (int i = 0; i < 63; ++i) {
    _Float16* h0in   = P.hist0H + (size_t)i * 32768;       _Float16* h0inL  = P.hist0L + (size_t)i * 32768;
    _Float16* h0out  = P.hist0H + (size_t)(i + 1) * 32768; _Float16* h0outL = P.hist0L + (size_t)(i + 1) * 32768;
    _Float16* h1in   = P.hist1H + (size_t)i * 32768;       _Float16* h1inL  = P.hist1L + (size_t)i * 32768;
    _Float16* h1out  = P.hist1H + (size_t)(i + 1) * 32768; _Float16* h1outL = P.hist1L + (size_t)(i + 1) * 32768;

    // ---- phase A: layer0 cell (token-rule x) ----
    int tok0 = 0, tok1 = 0;
    if (w < 8) {
      int b0 = lane & 15, b1 = 16 + (lane & 15);
      if (i == 0)              { tok0 = P.target[b0 * Tt_];     tok1 = P.target[b1 * Tt_]; }
      else if (P.tfm[i] > 0)   { tok0 = P.target[b0 * Tt_ + i]; tok1 = P.target[b1 * Tt_ + i]; }
      else {
        unsigned long long a0 = __hip_atomic_load(&P.amax[b0], __ATOMIC_RELAXED, __HIP_MEMORY_SCOPE_AGENT);
        unsigned long long a1 = __hip_atomic_load(&P.amax[b1], __ATOMIC_RELAXED, __HIP_MEMORY_SCOPE_AGENT);
        tok0 = (int)(~(unsigned)a0); tok1 = (int)(~(unsigned)a1);
      }
    }
    dcell16<2>(W0H, W0L, nullptr, nullptr, P.out_emb, tok0, tok1,
               h0in, h0inL, sScr, blk, tid);
    dcell_finish16(sScr, blk, tid, P.decbih, P.decbhh, c0, h0out, h0outL);
    gsync(P.flags, ++ep * NB_);

    // ---- phase B: layer1 cell ----
    if (blk == 0 && tid < 32)
      __hip_atomic_store(&P.amax[tid], 0ull, __ATOMIC_RELAXED, __HIP_MEMORY_SCOPE_AGENT);
    dcell16<0>(W1H, W1L, h0out, h0outL, nullptr, 0, 0,
               h1in, h1inL, sScr, blk, tid);
    dcell_finish16(sScr, blk, tid, P.decbih + 4096, P.decbhh + 4096, c1, h1out, h1outL);
    gsync(P.flags, ++ep * NB_);

    // ---- phase C: argmax-only projection (split-K wave pairs) ----
    bool needC = (i < 62) && (P.tfm[i + 1] == 0);
    if (needC) {
      int vt = blk * 8 + (w >> 1);
      int kh = w & 1;
      if (vt < 2000) {
        const _Float16* bH = P.Wo2H + ((size_t)vt * 32 + kh * 16) * 512 + lane * 8;
        const _Float16* bL = P.Wo2L + ((size_t)vt * 32 + kh * 16) * 512 + lane * 8;
        int kof = (lane >> 4) * 8;
        f4 accH[2] = {}, accM[2] = {};
#pragma unroll
        for (int kc = 0; kc < 4; ++kc) {
          h8 Bh[4], Bl[4], Ah[4][2], Al[4][2];
#pragma unroll
          for (int k4 = 0; k4 < 4; ++k4) {
            int ks = kc * 4 + k4;
            Bh[k4] = *(const h8*)(bH + ks * 512);
            Bl[k4] = *(const h8*)(bL + ks * 512);
            int kk = (kh * 16 + ks) * 32 + kof;
#pragma unroll
            for (int mt = 0; mt < 2; ++mt) {
              int brow = mt * 16 + (lane & 15);
              Ah[k4][mt] = *(const h8*)(h1out  + (size_t)brow * 1024 + kk);
              Al[k4][mt] = *(const h8*)(h1outL + (size_t)brow * 1024 + kk);
            }
          }
#pragma unroll
          for (int k4 = 0; k4 < 4; ++k4)
#pragma unroll
            for (int mt = 0; mt < 2; ++mt) {
              accH[mt] = MFMA16(Ah[k4][mt], Bh[k4], accH[mt]);
              accM[mt] = MFMA16(Ah[k4][mt], Bl[k4], accM[mt]);
              accM[mt] = MFMA16(Al[k4][mt], Bh[k4], accM[mt]);
            }
        }
#pragma unroll
        for (int mt = 0; mt < 2; ++mt)
#pragma unroll
          for (int r = 0; r < 4; ++r)
            sScr[w * 512 + (mt * 4 + r) * 64 + lane] =
                accH[mt][r] + accM[mt][r] * (1.0f / 2048.0f);
      }
      __syncthreads();
      if (vt < 2000 && kh == 0) {
        float biasv = P.bout[vt * 16 + (lane & 15)];
#pragma unroll
        for (int mt = 0; mt < 2; ++mt) {
          float vr[4];
#pragma unroll
          for (int r = 0; r < 4; ++r) {
            int idx = (mt * 4 + r) * 64 + lane;
            vr[r] = sScr[w * 512 + idx] + sScr[(w + 1) * 512 + idx] + biasv;
          }
#pragma unroll
          for (int r = 0; r < 4; ++r) {
            float v = vr[r];
            unsigned id = (unsigned)(vt * 16 + (lane & 15));
#pragma unroll
            for (int off = 1; off < 16; off <<= 1) {
              float ov = __shfl_xor(v, off, 64);
              unsigned oi = __shfl_xor(id, off, 64);
              if (ov > v || (ov == v && oi < id)) { v = ov; id = oi; }
            }
            if ((lane & 15) == 0) {
              unsigned kb = __float_as_uint(v);
              kb = (kb & 0x80000000u) ? ~kb : (kb | 0x80000000u);
              unsigned long long key = ((unsigned long long)kb << 32) | (unsigned)(~id);
              int b = mt * 16 + (lane >> 4) * 4 + r;
              unsigned long long cur = __hip_atomic_load(&P.amax[b], __ATOMIC_RELAXED,
                                                         __HIP_MEMORY_SCOPE_AGENT);
              if (cur < key) atomicMax(&P.amax[b], key);
            }
          }
        }
      }
      gsync(P.flags, ++ep * NB_);
    }
  }
}

// ============================ final batched output GEMM ============================
__global__ void __launch_bounds__(256, 2)
k_out(const _Float16* __restrict__ histH, const _Float16* __restrict__ histL,
      const _Float16* __restrict__ Wo2H, const _Float16* __restrict__ Wo2L,
      const float* __restrict__ bout, float* __restrict__ out) {
  int bid = blockIdx.x;          // 8000 = 500 nb x 16 mg
  int nb = bid / 16, mg = bid % 16;
  int w = threadIdx.x >> 6, lane = threadIdx.x & 63;
  int kof = (lane >> 4) * 8;
  int mt0 = mg * 8 + w * 2;
  f4 accH[2][4] = {}, accM[2][4] = {};
  for (int ks = 0; ks < 32; ++ks) {
    int kk = ks * 32 + kof;
    h8 Ah[2], Al[2];
#pragma unroll
    for (int mti = 0; mti < 2; ++mti) {
      int mt = mt0 + mti;
      if (mt < 126) {
        int m = mt * 16 + (lane & 15);
        int ii = m >> 5, b = m & 31;
        size_t ai = (size_t)(ii + 1) * 32768 + (size_t)b * 1024 + kk;
        Ah[mti] = *(const h8*)(histH + ai);
        Al[mti] = *(const h8*)(histL + ai);
      }
    }
#pragma unroll
    for (int nt = 0; nt < 4; ++nt) {
      size_t bi = ((size_t)(nb * 4 + nt) * 32 + ks) * 512 + lane * 8;
      h8 Bh = *(const h8*)(Wo2H + bi);
      h8 Bl = *(const h8*)(Wo2L + bi);
#pragma unroll
      for (int mti = 0; mti < 2; ++mti) {
        if (mt0 + mti < 126) {
          accH[mti][nt] = MFMA16(Ah[mti], Bh, accH[mti][nt]);
          accM[mti][nt] = MFMA16(Ah[mti], Bl, accM[mti][nt]);
          accM[mti][nt] = MFMA16(Al[mti], Bh, accM[mti][nt]);
        }
      }
    }
  }
#pragma unroll
  for (int mti = 0; mti < 2; ++mti) {
    int mt = mt0 + mti;
    if (mt >= 126) continue;
#pragma unroll
    for (int nt = 0; nt < 4; ++nt) {
      int vcol = (nb * 4 + nt) * 16 + (lane & 15);
      float bias = bout[vcol];
#pragma unroll
      for (int r = 0; r < 4; ++r) {
        int m = mt * 16 + (lane >> 4) * 4 + r;
        int ii = m >> 5, b = m & 31;
        out[(size_t)b * (Tt_ * V_) + (size_t)(ii + 1) * V_ + vcol] =
            accH[mti][nt][r] + accM[mti][nt][r] * (1.0f / 2048.0f) + bias;
      }
    }
  }
}

// ============================ host ============================

extern "C" void kernel_launch(void* const* d_in, const int* in_sizes, int n_in,
                              void* d_out, int out_size, void* d_ws, size_t ws_size,
                              hipStream_t stream) {
  const int*   itoks   = (const int*)d_in[0];
  const int*   target  = (const int*)d_in[1];
  const int*   tfm     = (const int*)d_in[2];
  const float* in_emb  = (const float*)d_in[3];
  const float* out_emb = (const float*)d_in[4];
  const float* encWih  = (const float*)d_in[5];
  const float* encWhh  = (const float*)d_in[6];
  const float* encbih  = (const float*)d_in[7];
  const float* encbhh  = (const float*)d_in[8];
  const float* decWih  = (const float*)d_in[9];
  const float* decWhh  = (const float*)d_in[10];
  const float* decbih  = (const float*)d_in[11];
  const float* decbhh  = (const float*)d_in[12];
  const float* Wout    = (const float*)d_in[13];
  const float* bout    = (const float*)d_in[14];
  float* out = (float*)d_out;

  char* ws = (char*)d_ws;
  size_t off = 0;
  auto alloc = [&](size_t bytes) { void* p = ws + off; off += (bytes + 255) & ~(size_t)255; return p; };
  _Float16* seqH  = (_Float16*)alloc((size_t)129 * 32768 * 2);
  _Float16* seqL  = (_Float16*)alloc((size_t)129 * 32768 * 2);
  _Float16* ehH   = (_Float16*)alloc((size_t)129 * 32768 * 2);
  _Float16* ehL   = (_Float16*)alloc((size_t)129 * 32768 * 2);
  _Float16* embH  = (_Float16*)alloc((size_t)128 * 32768 * 2);
  _Float16* embL  = (_Float16*)alloc((size_t)128 * 32768 * 2);
  _Float16* hist0H = (_Float16*)alloc((size_t)64 * 32768 * 2);
  _Float16* hist0L = (_Float16*)alloc((size_t)64 * 32768 * 2);
  _Float16* hist1H = (_Float16*)alloc((size_t)64 * 32768 * 2);
  _Float16* hist1L = (_Float16*)alloc((size_t)64 * 32768 * 2);
  float*    cb0   = (float*)alloc((size_t)32 * 1024 * 4);
  float*    cb1   = (float*)alloc((size_t)32 * 1024 * 4);
  _Float16* dW2H  = (_Float16*)alloc((size_t)2 * 8388608 * 2);
  _Float16* dW2L  = (_Float16*)alloc((size_t)2 * 8388608 * 2);
  _Float16* Wo2H  = (_Float16*)alloc((size_t)2000 * 32 * 512 * 2);
  _Float16* Wo2L  = (_Float16*)alloc((size_t)2000 * 32 * 512 * 2);
  unsigned long long* amax = (unsigned long long*)alloc(32 * 8);
  unsigned* encF = (unsigned*)alloc(NB_ * 4 * 4);
  unsigned* decF = (unsigned*)alloc(NB_ * 4 * 4);
  if (off > ws_size) return;

  k_prep0<<<1024, 256, 0, stream>>>(out, seqH, seqL, ehH, ehL, encF, decF);
  k_dw2<<<8192, 256, 0, stream>>>(decWih, decWhh, dW2H, dW2L);
  k_wo2<<<16000, 256, 0, stream>>>(Wout, Wo2H, Wo2L);
  k_emb<<<4096, 128, 0, stream>>>(itoks, in_emb, embH, embL);

  EP E;
  E.encWih = encWih; E.encWhh = encWhh; E.encbih = encbih; E.encbhh = encbhh;
  E.embH = embH; E.embL = embL;
  E.seqH = seqH; E.seqL = seqL; E.ehH = ehH; E.ehL = ehL;
  E.h0s0H = hist0H; E.h0s0L = hist0L; E.h1s0H = hist1H; E.h1s0L = hist1L;
  E.cb0 = cb0; E.cb1 = cb1; E.flags = encF;
  void* eargs[] = { &E };
  hipLaunchCooperativeKernel((void*)voice_enc, dim3(NB_), dim3(512), eargs, 0, stream);

  DP D;
  D.out_emb = out_emb; D.target = target; D.tfm = tfm;
  D.dW2H = dW2H; D.dW2L = dW2L; D.decbih = decbih; D.decbhh = decbhh;
  D.Wo2H = Wo2H; D.Wo2L = Wo2L; D.bout = bout;
  D.hist0H = hist0H; D.hist0L = hist0L; D.hist1H = hist1H; D.hist1L = hist1L;
  D.cb0 = cb0; D.cb1 = cb1; D.amax = amax; D.flags = decF;
  void* dargs[] = { &D };
  hipLaunchCooperativeKernel((void*)voice_dec, dim3(NB_), dim3(1024), dargs, 0, stream);

  k_out<<<8000, 256, 0, stream>>>(hist1H, hist1L, Wo2H, Wo2L, bout, out);
}